// Round 1
// baseline (10304.777 us; speedup 1.0000x reference)
//
#include <hip/hip_runtime.h>

#define NB 8
#define NT 4096
#define NM 32768
#define ND 128

// ---- bf16 helpers (RNE) ----
__device__ __forceinline__ unsigned short f2bf(float x) {
  unsigned u = __float_as_uint(x);
  u += 0x7FFFu + ((u >> 16) & 1u);
  return (unsigned short)(u >> 16);
}
__device__ __forceinline__ float bf2f(unsigned short h) {
  return __uint_as_float(((unsigned)h) << 16);
}

// ---------------- scatter: upd[b, e0[m], ch] += A[b,m] * relu?(xn[b, e1[m], ch]) ----------------
__global__ __launch_bounds__(256) void k_scatter(
    const float* __restrict__ xn, const float* __restrict__ A,
    const int* __restrict__ edge, float* __restrict__ upd, int doRelu)
{
  unsigned idx = blockIdx.x * 256u + threadIdx.x;   // total NB*NM*2*(ND/4) = 2^24
  int d4 = (idx & 31) << 2;
  int ch = (idx >> 5) & 1;
  int m  = (idx >> 6) & (NM - 1);
  int b  = idx >> 21;
  int e0 = edge[m];
  int e1 = edge[NM + m];
  float a = A[b * NM + m];
  const float4 v = *(const float4*)(xn + ((b * NT + e1) * 2 + ch) * ND + d4);
  float vx = v.x, vy = v.y, vz = v.z, vw = v.w;
  if (doRelu) {
    vx = fmaxf(vx, 0.f); vy = fmaxf(vy, 0.f);
    vz = fmaxf(vz, 0.f); vw = fmaxf(vw, 0.f);
  }
  float* dst = upd + ((b * NT + e0) * 2 + ch) * ND + d4;
  unsafeAtomicAdd(dst + 0, vx * a);
  unsafeAtomicAdd(dst + 1, vy * a);
  unsafeAtomicAdd(dst + 2, vz * a);
  unsafeAtomicAdd(dst + 3, vw * a);
}

// ---------------- node linear: xn = (relu?(xn) + upd) @ W + b   (in place, pre-relu stored) ----
__global__ __launch_bounds__(256) void k_nodelin(
    float* __restrict__ xn, const float* __restrict__ upd,
    const float* __restrict__ W, const float* __restrict__ bias, int doReluIn)
{
  __shared__ float Ws[ND * ND];     // 64 KB
  __shared__ float xs[32][ND];      // 16 KB  -> 80 KB total, 2 blocks/CU
  const int t = threadIdx.x;
  for (int i = t; i < ND * ND; i += 256) Ws[i] = W[i];
  const int rowBase = blockIdx.x << 5;
  for (int p = 0; p < 16; ++p) {
    int idx = (p << 8) + t;
    int r = idx >> 7, d = idx & 127;
    float x = xn[(rowBase + r) * ND + d];
    if (doReluIn) x = fmaxf(x, 0.f);
    xs[r][d] = x + upd[(rowBase + r) * ND + d];
  }
  const int c4 = (t & 31) << 2;
  const int rg = t >> 5;
  float4 bv = *(const float4*)(bias + c4);
  __syncthreads();
  float acc[4][4];
  #pragma unroll
  for (int r = 0; r < 4; ++r)
    #pragma unroll
    for (int c = 0; c < 4; ++c) acc[r][c] = 0.f;
  for (int k = 0; k < ND; k += 4) {
    float4 sv[4];
    #pragma unroll
    for (int r = 0; r < 4; ++r) sv[r] = *(const float4*)&xs[(rg << 2) + r][k];
    #pragma unroll
    for (int j = 0; j < 4; ++j) {
      float4 w = *(const float4*)&Ws[(k + j) * ND + c4];
      #pragma unroll
      for (int r = 0; r < 4; ++r) {
        float s = ((const float*)&sv[r])[j];
        acc[r][0] += s * w.x; acc[r][1] += s * w.y;
        acc[r][2] += s * w.z; acc[r][3] += s * w.w;
      }
    }
  }
  #pragma unroll
  for (int r = 0; r < 4; ++r) {
    float4 o;
    o.x = acc[r][0] + bv.x; o.y = acc[r][1] + bv.y;
    o.z = acc[r][2] + bv.z; o.w = acc[r][3] + bv.w;
    *(float4*)&xn[(rowBase + (rg << 2) + r) * ND + c4] = o;
  }
}

// ---------------- edge: xe = relu?((xe + (ei+ej)@Wm + bm) @ We + be)   (in place) --------------
__global__ __launch_bounds__(256) void k_edge(
    const float* __restrict__ xn, float* __restrict__ xe,
    const int* __restrict__ edge,
    const float* __restrict__ Wm, const float* __restrict__ bm,
    const float* __restrict__ We, const float* __restrict__ be,
    int doReluOut)
{
  __shared__ unsigned short Wms[ND * ND];   // 32 KB (bf16)
  __shared__ unsigned short Wes[ND * ND];   // 32 KB
  __shared__ float sbuf[32][ND];            // 16 KB  -> 80 KB total, 2 blocks/CU
  const int t = threadIdx.x;
  for (int i = t; i < ND * ND; i += 256) {
    Wms[i] = f2bf(Wm[i]);
    Wes[i] = f2bf(We[i]);
  }
  const int c4 = (t & 31) << 2;
  const int rg = t >> 5;                    // 0..7, 4 rows each
  float4 bmv = *(const float4*)(bm + c4);
  float4 bev = *(const float4*)(be + c4);
  __syncthreads();
  const int nTiles = (NB * NM * 4) / 32;    // 32768
  for (int tile = blockIdx.x; tile < nTiles; tile += gridDim.x) {
    const int rowBase = tile << 5;
    // stage s = ei + ej  (32 rows x 128)
    #pragma unroll
    for (int p = 0; p < 16; ++p) {
      int idx = (p << 8) + t;
      int r = idx >> 7, d = idx & 127;
      int grow = rowBase + r;
      int cch = grow & 3;
      int m = (grow >> 2) & (NM - 1);
      int b = grow >> 17;
      int e0 = edge[m], e1 = edge[NM + m];
      sbuf[r][d] = xn[((b * NT + e0) * 2 + (cch >> 1)) * ND + d]
                 + xn[((b * NT + e1) * 2 + (cch & 1)) * ND + d];
    }
    __syncthreads();
    // phase A: tval = s @ Wm (keep in regs)
    float acc[4][4];
    #pragma unroll
    for (int r = 0; r < 4; ++r)
      #pragma unroll
      for (int c = 0; c < 4; ++c) acc[r][c] = 0.f;
    for (int k = 0; k < ND; k += 4) {
      float4 sv[4];
      #pragma unroll
      for (int r = 0; r < 4; ++r) sv[r] = *(const float4*)&sbuf[(rg << 2) + r][k];
      #pragma unroll
      for (int j = 0; j < 4; ++j) {
        ushort4 wu = *(const ushort4*)&Wms[(k + j) * ND + c4];
        float w0 = bf2f(wu.x), w1 = bf2f(wu.y), w2 = bf2f(wu.z), w3 = bf2f(wu.w);
        #pragma unroll
        for (int r = 0; r < 4; ++r) {
          float s = ((const float*)&sv[r])[j];
          acc[r][0] += s * w0; acc[r][1] += s * w1;
          acc[r][2] += s * w2; acc[r][3] += s * w3;
        }
      }
    }
    __syncthreads();   // everyone done reading sbuf
    // v = xe + tval + bm  -> sbuf
    #pragma unroll
    for (int r = 0; r < 4; ++r) {
      int grow = rowBase + (rg << 2) + r;
      float4 xev = *(const float4*)&xe[(size_t)grow * ND + c4];
      float4 v;
      v.x = xev.x + acc[r][0] + bmv.x;
      v.y = xev.y + acc[r][1] + bmv.y;
      v.z = xev.z + acc[r][2] + bmv.z;
      v.w = xev.w + acc[r][3] + bmv.w;
      *(float4*)&sbuf[(rg << 2) + r][c4] = v;
    }
    __syncthreads();
    // phase B: out = v @ We + be
    #pragma unroll
    for (int r = 0; r < 4; ++r)
      #pragma unroll
      for (int c = 0; c < 4; ++c) acc[r][c] = 0.f;
    for (int k = 0; k < ND; k += 4) {
      float4 sv[4];
      #pragma unroll
      for (int r = 0; r < 4; ++r) sv[r] = *(const float4*)&sbuf[(rg << 2) + r][k];
      #pragma unroll
      for (int j = 0; j < 4; ++j) {
        ushort4 wu = *(const ushort4*)&Wes[(k + j) * ND + c4];
        float w0 = bf2f(wu.x), w1 = bf2f(wu.y), w2 = bf2f(wu.z), w3 = bf2f(wu.w);
        #pragma unroll
        for (int r = 0; r < 4; ++r) {
          float s = ((const float*)&sv[r])[j];
          acc[r][0] += s * w0; acc[r][1] += s * w1;
          acc[r][2] += s * w2; acc[r][3] += s * w3;
        }
      }
    }
    #pragma unroll
    for (int r = 0; r < 4; ++r) {
      int grow = rowBase + (rg << 2) + r;
      float4 o;
      o.x = acc[r][0] + bev.x; o.y = acc[r][1] + bev.y;
      o.z = acc[r][2] + bev.z; o.w = acc[r][3] + bev.w;
      if (doReluOut) {
        o.x = fmaxf(o.x, 0.f); o.y = fmaxf(o.y, 0.f);
        o.z = fmaxf(o.z, 0.f); o.w = fmaxf(o.w, 0.f);
      }
      *(float4*)&xe[(size_t)grow * ND + c4] = o;
    }
    __syncthreads();
  }
}

// ---------------- readout: out = lin(relu(lin(relu(lin(x,W1,b1)),W2,b2)),W3,b3) ----------------
__global__ __launch_bounds__(256) void k_readout(
    const float* __restrict__ in, int nTiles,
    const float* __restrict__ W1, const float* __restrict__ b1,
    const float* __restrict__ W2, const float* __restrict__ b2,
    const float* __restrict__ W3, const float* __restrict__ b3,
    float* __restrict__ out)
{
  __shared__ unsigned short W1s[ND * 2 * ND];   // 64 KB (bf16)
  __shared__ unsigned short W2s[2 * ND * ND];   // 64 KB
  __shared__ float xbuf[16][ND];                // 8 KB
  __shared__ float h1buf[16][2 * ND];           // 16 KB  -> 152 KB, 1 block/CU
  const int t = threadIdx.x;
  for (int i = t; i < ND * 2 * ND; i += 256) {
    W1s[i] = f2bf(W1[i]);
    W2s[i] = f2bf(W2[i]);
  }
  const int lane = t & 63;
  const float w3a = W3[lane], w3b = W3[lane + 64];
  const float b3v = b3[0];
  const int c4a = (t & 63) << 2;   // phase-1 cols 0..255
  const int rga = t >> 6;          // 4 row-groups x 4 rows
  float4 b1v = *(const float4*)(b1 + c4a);
  const int c4b = (t & 31) << 2;   // phase-2 cols 0..127
  const int rgb = t >> 5;          // 8 row-groups x 2 rows
  float4 b2v = *(const float4*)(b2 + c4b);
  __syncthreads();
  for (int tile = blockIdx.x; tile < nTiles; tile += gridDim.x) {
    const int rowBase = tile << 4;
    for (int p = 0; p < 8; ++p) {
      int idx = (p << 8) + t;
      int r = idx >> 7, d = idx & 127;
      xbuf[r][d] = in[(size_t)(rowBase + r) * ND + d];
    }
    __syncthreads();
    // phase 1: h1 = relu(x @ W1 + b1)   16 x 256
    {
      float acc[4][4];
      #pragma unroll
      for (int r = 0; r < 4; ++r)
        #pragma unroll
        for (int c = 0; c < 4; ++c) acc[r][c] = 0.f;
      for (int k = 0; k < ND; k += 4) {
        float4 sv[4];
        #pragma unroll
        for (int r = 0; r < 4; ++r) sv[r] = *(const float4*)&xbuf[(rga << 2) + r][k];
        #pragma unroll
        for (int j = 0; j < 4; ++j) {
          ushort4 wu = *(const ushort4*)&W1s[(k + j) * (2 * ND) + c4a];
          float w0 = bf2f(wu.x), w1 = bf2f(wu.y), w2 = bf2f(wu.z), w3 = bf2f(wu.w);
          #pragma unroll
          for (int r = 0; r < 4; ++r) {
            float s = ((const float*)&sv[r])[j];
            acc[r][0] += s * w0; acc[r][1] += s * w1;
            acc[r][2] += s * w2; acc[r][3] += s * w3;
          }
        }
      }
      #pragma unroll
      for (int r = 0; r < 4; ++r) {
        h1buf[(rga << 2) + r][c4a + 0] = fmaxf(acc[r][0] + b1v.x, 0.f);
        h1buf[(rga << 2) + r][c4a + 1] = fmaxf(acc[r][1] + b1v.y, 0.f);
        h1buf[(rga << 2) + r][c4a + 2] = fmaxf(acc[r][2] + b1v.z, 0.f);
        h1buf[(rga << 2) + r][c4a + 3] = fmaxf(acc[r][3] + b1v.w, 0.f);
      }
    }
    __syncthreads();
    // phase 2: h2 = relu(h1 @ W2 + b2)   16 x 128  -> xbuf
    {
      float acc[2][4];
      #pragma unroll
      for (int r = 0; r < 2; ++r)
        #pragma unroll
        for (int c = 0; c < 4; ++c) acc[r][c] = 0.f;
      for (int k = 0; k < 2 * ND; k += 4) {
        float4 sv[2];
        #pragma unroll
        for (int r = 0; r < 2; ++r) sv[r] = *(const float4*)&h1buf[(rgb << 1) + r][k];
        #pragma unroll
        for (int j = 0; j < 4; ++j) {
          ushort4 wu = *(const ushort4*)&W2s[(k + j) * ND + c4b];
          float w0 = bf2f(wu.x), w1 = bf2f(wu.y), w2 = bf2f(wu.z), w3 = bf2f(wu.w);
          #pragma unroll
          for (int r = 0; r < 2; ++r) {
            float s = ((const float*)&sv[r])[j];
            acc[r][0] += s * w0; acc[r][1] += s * w1;
            acc[r][2] += s * w2; acc[r][3] += s * w3;
          }
        }
      }
      #pragma unroll
      for (int r = 0; r < 2; ++r) {
        xbuf[(rgb << 1) + r][c4b + 0] = fmaxf(acc[r][0] + b2v.x, 0.f);
        xbuf[(rgb << 1) + r][c4b + 1] = fmaxf(acc[r][1] + b2v.y, 0.f);
        xbuf[(rgb << 1) + r][c4b + 2] = fmaxf(acc[r][2] + b2v.z, 0.f);
        xbuf[(rgb << 1) + r][c4b + 3] = fmaxf(acc[r][3] + b2v.w, 0.f);
      }
    }
    __syncthreads();
    // phase 3: out = h2 . W3 + b3   (wave per 4 rows)
    {
      const int wv = t >> 6;
      #pragma unroll
      for (int rr = 0; rr < 4; ++rr) {
        int r = (wv << 2) + rr;
        float p = xbuf[r][lane] * w3a + xbuf[r][lane + 64] * w3b;
        p += __shfl_down(p, 32);
        p += __shfl_down(p, 16);
        p += __shfl_down(p, 8);
        p += __shfl_down(p, 4);
        p += __shfl_down(p, 2);
        p += __shfl_down(p, 1);
        if (lane == 0) out[rowBase + r] = p + b3v;
      }
    }
    __syncthreads();
  }
}

extern "C" void kernel_launch(void* const* d_in, const int* in_sizes, int n_in,
                              void* d_out, int out_size, void* d_ws, size_t ws_size,
                              hipStream_t stream)
{
  const float* x1     = (const float*)d_in[0];
  const float* x2     = (const float*)d_in[1];
  const float* Ac     = (const float*)d_in[2];
  const int*   edge   = (const int*)d_in[3];
  const float* node_W = (const float*)d_in[4];
  const float* node_b = (const float*)d_in[5];
  const float* mlp_W  = (const float*)d_in[6];
  const float* mlp_b  = (const float*)d_in[7];
  const float* egL_W  = (const float*)d_in[8];
  const float* egL_b  = (const float*)d_in[9];
  const float* nro_W1 = (const float*)d_in[10];
  const float* nro_b1 = (const float*)d_in[11];
  const float* nro_W2 = (const float*)d_in[12];
  const float* nro_b2 = (const float*)d_in[13];
  const float* nro_W3 = (const float*)d_in[14];
  const float* nro_b3 = (const float*)d_in[15];
  const float* ero_W1 = (const float*)d_in[16];
  const float* ero_b1 = (const float*)d_in[17];
  const float* ero_W2 = (const float*)d_in[18];
  const float* ero_b2 = (const float*)d_in[19];
  const float* ero_W3 = (const float*)d_in[20];
  const float* ero_b3 = (const float*)d_in[21];
  float* out = (float*)d_out;

  const size_t xnElems = (size_t)NB * NT * 2 * ND;       // 8,388,608
  const size_t xeElems = (size_t)NB * NM * 4 * ND;       // 134,217,728
  if (ws_size < (xnElems * 2 + xeElems) * sizeof(float)) return;

  float* xn  = (float*)d_ws;
  float* upd = xn + xnElems;
  float* xe  = upd + xnElems;

  hipMemcpyAsync(xn, x1, xnElems * sizeof(float), hipMemcpyDeviceToDevice, stream);
  hipMemcpyAsync(xe, x2, xeElems * sizeof(float), hipMemcpyDeviceToDevice, stream);

  for (int i = 0; i < 3; ++i) {
    hipMemsetAsync(upd, 0, xnElems * sizeof(float), stream);
    k_scatter<<<65536, 256, 0, stream>>>(xn, Ac, edge, upd, i > 0);
    k_nodelin<<<2048, 256, 0, stream>>>(xn, upd, node_W + i * ND * ND, node_b + i * ND, i > 0);
    k_edge<<<2048, 256, 0, stream>>>(xn, xe, edge,
                                     mlp_W + i * ND * ND, mlp_b + i * ND,
                                     egL_W + i * ND * ND, egL_b + i * ND, i < 2);
  }
  k_readout<<<2048, 256, 0, stream>>>(xn, (NB * NT * 2) / 16,
                                      nro_W1, nro_b1, nro_W2, nro_b2, nro_W3, nro_b3,
                                      out);
  k_readout<<<2048, 256, 0, stream>>>(xe, (NB * NM * 4) / 16,
                                      ero_W1, ero_b1, ero_W2, ero_b2, ero_W3, ero_b3,
                                      out + NB * NT * 2);
}

// Round 2
// 4994.030 us; speedup vs baseline: 2.0634x; 2.0634x over previous
//
#include <hip/hip_runtime.h>

#define NB 8
#define NT 4096
#define NM 32768
#define ND 128

typedef __attribute__((ext_vector_type(8))) short bf16x8;
typedef __attribute__((ext_vector_type(4))) float f32x4;
typedef __attribute__((ext_vector_type(4))) unsigned int u32x4;

#define MFMA(a,b,c) __builtin_amdgcn_mfma_f32_16x16x32_bf16(a,b,c,0,0,0)

// ---- bf16 helpers (RNE) ----
__device__ __forceinline__ unsigned short f2bf(float x) {
  unsigned u = __float_as_uint(x);
  u += 0x7FFFu + ((u >> 16) & 1u);
  return (unsigned short)(u >> 16);
}
__device__ __forceinline__ float bf2f(unsigned short h) {
  return __uint_as_float(((unsigned)h) << 16);
}

// XOR-swizzled LDS fragment read: 8 consecutive bf16 at (row, kByte)
__device__ __forceinline__ bf16x8 ldsFrag(const char* lds, int row, int kByte, int rowStride) {
  return *(const bf16x8*)(lds + ((row * rowStride + kByte) ^ ((row & 7) << 4)));
}

// Stage W[K][N] (f32, row-major) -> LDS WT[N][K] bf16, XOR-swizzled rows.
// khShift = log2(K/8). 256 threads.
__device__ __forceinline__ void stageWT(const float* __restrict__ W, char* lds,
                                        int K, int N, int khShift) {
  const int khn = 1 << khShift;
  const int rowStride = K * 2;
  for (int i = threadIdx.x; i < (N << khShift); i += 256) {
    int n = i >> khShift, kh = i & (khn - 1);
    int k0 = kh << 3;
    unsigned short tmp[8];
    #pragma unroll
    for (int j = 0; j < 8; ++j) tmp[j] = f2bf(W[(k0 + j) * N + n]);
    *(u32x4*)(lds + ((n * rowStride + k0 * 2) ^ ((n & 7) << 4))) = *(u32x4*)tmp;
  }
}

// ---------------- scatter: upd[b, e0[m], ch] += A[b,m] * relu?(xn[b, e1[m], ch]) --------------
__global__ __launch_bounds__(256) void k_scatter(
    const float* __restrict__ xn, const float* __restrict__ A,
    const int* __restrict__ edge, float* __restrict__ upd, int doRelu)
{
  unsigned idx = blockIdx.x * 256u + threadIdx.x;
  int d4 = (idx & 31) << 2;
  int ch = (idx >> 5) & 1;
  int m  = (idx >> 6) & (NM - 1);
  int b  = idx >> 21;
  int e0 = edge[m];
  int e1 = edge[NM + m];
  float a = A[b * NM + m];
  const float4 v = *(const float4*)(xn + ((b * NT + e1) * 2 + ch) * ND + d4);
  float vx = v.x, vy = v.y, vz = v.z, vw = v.w;
  if (doRelu) {
    vx = fmaxf(vx, 0.f); vy = fmaxf(vy, 0.f);
    vz = fmaxf(vz, 0.f); vw = fmaxf(vw, 0.f);
  }
  float* dst = upd + ((b * NT + e0) * 2 + ch) * ND + d4;
  unsafeAtomicAdd(dst + 0, vx * a);
  unsafeAtomicAdd(dst + 1, vy * a);
  unsafeAtomicAdd(dst + 2, vz * a);
  unsafeAtomicAdd(dst + 3, vw * a);
}

// ---------------- node linear (f32, small): xn = (relu?(xn) + upd) @ W + b -------------------
__global__ __launch_bounds__(256) void k_nodelin(
    float* __restrict__ xn, const float* __restrict__ upd,
    const float* __restrict__ W, const float* __restrict__ bias, int doReluIn)
{
  __shared__ float Ws[ND * ND];
  __shared__ float xs[32][ND];
  const int t = threadIdx.x;
  for (int i = t; i < ND * ND; i += 256) Ws[i] = W[i];
  const int rowBase = blockIdx.x << 5;
  for (int p = 0; p < 16; ++p) {
    int idx = (p << 8) + t;
    int r = idx >> 7, d = idx & 127;
    float x = xn[(rowBase + r) * ND + d];
    if (doReluIn) x = fmaxf(x, 0.f);
    xs[r][d] = x + upd[(rowBase + r) * ND + d];
  }
  const int c4 = (t & 31) << 2;
  const int rg = t >> 5;
  float4 bv = *(const float4*)(bias + c4);
  __syncthreads();
  float acc[4][4];
  #pragma unroll
  for (int r = 0; r < 4; ++r)
    #pragma unroll
    for (int c = 0; c < 4; ++c) acc[r][c] = 0.f;
  for (int k = 0; k < ND; k += 4) {
    float4 sv[4];
    #pragma unroll
    for (int r = 0; r < 4; ++r) sv[r] = *(const float4*)&xs[(rg << 2) + r][k];
    #pragma unroll
    for (int j = 0; j < 4; ++j) {
      float4 w = *(const float4*)&Ws[(k + j) * ND + c4];
      #pragma unroll
      for (int r = 0; r < 4; ++r) {
        float s = ((const float*)&sv[r])[j];
        acc[r][0] += s * w.x; acc[r][1] += s * w.y;
        acc[r][2] += s * w.z; acc[r][3] += s * w.w;
      }
    }
  }
  #pragma unroll
  for (int r = 0; r < 4; ++r) {
    float4 o;
    o.x = acc[r][0] + bv.x; o.y = acc[r][1] + bv.y;
    o.z = acc[r][2] + bv.z; o.w = acc[r][3] + bv.w;
    *(float4*)&xn[(rowBase + (rg << 2) + r) * ND + c4] = o;
  }
}

// ---------------- edge layer (MFMA): xe = relu?((xe + (ei+ej)@Wm + bm) @ We + be) ------------
__global__ __launch_bounds__(256) void k_edge_mfma(
    const float* __restrict__ xn, float* xe,
    const int* __restrict__ edge,
    const float* __restrict__ Wm, const float* __restrict__ bm,
    const float* __restrict__ We, const float* __restrict__ be,
    int doReluOut)
{
  __shared__ char WmT[128 * 256];   // [n][k] bf16 swizzled, 32 KB
  __shared__ char WeT[128 * 256];   // 32 KB
  __shared__ char sA[32 * 256];     // 32 rows x 128 bf16, 8 KB
  const int t = threadIdx.x;
  stageWT(Wm, WmT, 128, 128, 4);
  stageWT(We, WeT, 128, 128, 4);
  const int w   = t >> 6;     // wave 0..3 -> cols w*32 .. w*32+31
  const int l   = t & 63;
  const int l15 = l & 15;
  const int lg  = l >> 4;
  float bmv[2], bev[2];
  #pragma unroll
  for (int fc = 0; fc < 2; ++fc) {
    int col = w * 32 + fc * 16 + l15;
    bmv[fc] = bm[col];
    bev[fc] = be[col];
  }
  // staging geometry (per tile): row = t>>3, 16B slots h = (t&7), (t&7)+8
  const int srow = t >> 3;
  __syncthreads();

  const int nTiles = (NB * NM * 4) / 32;   // 32768
  for (int tile = blockIdx.x; tile < nTiles; tile += gridDim.x) {
    const int rowBase = tile << 5;
    // ---- stage sA = bf16(xn[e0,ni] + xn[e1,nj]) ----
    {
      int grow = rowBase + srow;
      int cch = grow & 3;
      int m = (grow >> 2) & (NM - 1);
      int b = grow >> 17;
      int e0 = edge[m], e1 = edge[NM + m];
      const float* p0 = xn + (size_t)((b * NT + e0) * 2 + (cch >> 1)) * ND;
      const float* p1 = xn + (size_t)((b * NT + e1) * 2 + (cch & 1)) * ND;
      #pragma unroll
      for (int hh = 0; hh < 2; ++hh) {
        int h = (t & 7) + hh * 8;
        float4 a0 = *(const float4*)(p0 + h * 8);
        float4 a1 = *(const float4*)(p0 + h * 8 + 4);
        float4 c0 = *(const float4*)(p1 + h * 8);
        float4 c1 = *(const float4*)(p1 + h * 8 + 4);
        unsigned short tmp[8];
        tmp[0] = f2bf(a0.x + c0.x); tmp[1] = f2bf(a0.y + c0.y);
        tmp[2] = f2bf(a0.z + c0.z); tmp[3] = f2bf(a0.w + c0.w);
        tmp[4] = f2bf(a1.x + c1.x); tmp[5] = f2bf(a1.y + c1.y);
        tmp[6] = f2bf(a1.z + c1.z); tmp[7] = f2bf(a1.w + c1.w);
        *(u32x4*)(sA + ((srow * 256 + h * 16) ^ ((srow & 7) << 4))) = *(u32x4*)tmp;
      }
    }
    __syncthreads();
    // ---- phase A: T = sA @ Wm ----
    f32x4 acc[2][2];
    #pragma unroll
    for (int fr = 0; fr < 2; ++fr)
      #pragma unroll
      for (int fc = 0; fc < 2; ++fc) acc[fr][fc] = (f32x4){0.f, 0.f, 0.f, 0.f};
    #pragma unroll
    for (int ks = 0; ks < 4; ++ks) {
      int kb = ks * 64 + lg * 16;
      bf16x8 a0 = ldsFrag(sA, l15,      kb, 256);
      bf16x8 a1 = ldsFrag(sA, 16 + l15, kb, 256);
      bf16x8 b0 = ldsFrag(WmT, w * 32 + l15,      kb, 256);
      bf16x8 b1 = ldsFrag(WmT, w * 32 + 16 + l15, kb, 256);
      acc[0][0] = MFMA(a0, b0, acc[0][0]);
      acc[0][1] = MFMA(a0, b1, acc[0][1]);
      acc[1][0] = MFMA(a1, b0, acc[1][0]);
      acc[1][1] = MFMA(a1, b1, acc[1][1]);
    }
    __syncthreads();
    // ---- v = xe + T + bm -> sA (bf16) ----
    #pragma unroll
    for (int fr = 0; fr < 2; ++fr)
      #pragma unroll
      for (int fc = 0; fc < 2; ++fc) {
        int col = w * 32 + fc * 16 + l15;
        #pragma unroll
        for (int i = 0; i < 4; ++i) {
          int r = fr * 16 + lg * 4 + i;
          float v = xe[(size_t)(rowBase + r) * ND + col] + acc[fr][fc][i] + bmv[fc];
          *(unsigned short*)(sA + ((r * 256 + col * 2) ^ ((r & 7) << 4))) = f2bf(v);
        }
      }
    __syncthreads();
    // ---- phase B: O = v @ We ----
    f32x4 acc2[2][2];
    #pragma unroll
    for (int fr = 0; fr < 2; ++fr)
      #pragma unroll
      for (int fc = 0; fc < 2; ++fc) acc2[fr][fc] = (f32x4){0.f, 0.f, 0.f, 0.f};
    #pragma unroll
    for (int ks = 0; ks < 4; ++ks) {
      int kb = ks * 64 + lg * 16;
      bf16x8 a0 = ldsFrag(sA, l15,      kb, 256);
      bf16x8 a1 = ldsFrag(sA, 16 + l15, kb, 256);
      bf16x8 b0 = ldsFrag(WeT, w * 32 + l15,      kb, 256);
      bf16x8 b1 = ldsFrag(WeT, w * 32 + 16 + l15, kb, 256);
      acc2[0][0] = MFMA(a0, b0, acc2[0][0]);
      acc2[0][1] = MFMA(a0, b1, acc2[0][1]);
      acc2[1][0] = MFMA(a1, b0, acc2[1][0]);
      acc2[1][1] = MFMA(a1, b1, acc2[1][1]);
    }
    __syncthreads();   // sA free for next tile
    // ---- epilogue: xe = relu?(O + be) ----
    #pragma unroll
    for (int fr = 0; fr < 2; ++fr)
      #pragma unroll
      for (int fc = 0; fc < 2; ++fc) {
        int col = w * 32 + fc * 16 + l15;
        #pragma unroll
        for (int i = 0; i < 4; ++i) {
          int r = fr * 16 + lg * 4 + i;
          float o = acc2[fr][fc][i] + bev[fc];
          if (doReluOut) o = fmaxf(o, 0.f);
          xe[(size_t)(rowBase + r) * ND + col] = o;
        }
      }
  }
}

// ---------------- readout stage 1 (MFMA): h1 = relu(x @ W1 + b1), bf16 in-place --------------
__global__ __launch_bounds__(256) void k_ro1(
    const float* inF,              // rows x 128 f32 (aliases outH!)
    unsigned short* outH,          // rows x 256 bf16
    int nTiles,
    const float* __restrict__ W1, const float* __restrict__ b1)
{
  __shared__ char WT[256 * 256];   // [256 n][128 k] bf16 swizzled, 64 KB
  __shared__ char sA[32 * 256];    // 8 KB
  const int t = threadIdx.x;
  stageWT(W1, WT, 128, 256, 4);
  const int w   = t >> 6;          // wave -> cols w*64 .. w*64+63
  const int l   = t & 63;
  const int l15 = l & 15;
  const int lg  = l >> 4;
  float b1v[4];
  #pragma unroll
  for (int fc = 0; fc < 4; ++fc) b1v[fc] = b1[w * 64 + fc * 16 + l15];
  const int srow = t >> 3;
  __syncthreads();

  for (int tile = blockIdx.x; tile < nTiles; tile += gridDim.x) {
    const int rowBase = tile << 5;
    {
      const float* p0 = inF + (size_t)(rowBase + srow) * ND;
      #pragma unroll
      for (int hh = 0; hh < 2; ++hh) {
        int h = (t & 7) + hh * 8;
        float4 a0 = *(const float4*)(p0 + h * 8);
        float4 a1 = *(const float4*)(p0 + h * 8 + 4);
        unsigned short tmp[8];
        tmp[0] = f2bf(a0.x); tmp[1] = f2bf(a0.y);
        tmp[2] = f2bf(a0.z); tmp[3] = f2bf(a0.w);
        tmp[4] = f2bf(a1.x); tmp[5] = f2bf(a1.y);
        tmp[6] = f2bf(a1.z); tmp[7] = f2bf(a1.w);
        *(u32x4*)(sA + ((srow * 256 + h * 16) ^ ((srow & 7) << 4))) = *(u32x4*)tmp;
      }
    }
    __syncthreads();
    f32x4 acc[2][4];
    #pragma unroll
    for (int fr = 0; fr < 2; ++fr)
      #pragma unroll
      for (int fc = 0; fc < 4; ++fc) acc[fr][fc] = (f32x4){0.f, 0.f, 0.f, 0.f};
    #pragma unroll
    for (int ks = 0; ks < 4; ++ks) {
      int kb = ks * 64 + lg * 16;
      bf16x8 a0 = ldsFrag(sA, l15,      kb, 256);
      bf16x8 a1 = ldsFrag(sA, 16 + l15, kb, 256);
      #pragma unroll
      for (int fc = 0; fc < 4; ++fc) {
        bf16x8 bfr = ldsFrag(WT, w * 64 + fc * 16 + l15, kb, 256);
        acc[0][fc] = MFMA(a0, bfr, acc[0][fc]);
        acc[1][fc] = MFMA(a1, bfr, acc[1][fc]);
      }
    }
    __syncthreads();   // sA free for next tile
    #pragma unroll
    for (int fr = 0; fr < 2; ++fr)
      #pragma unroll
      for (int fc = 0; fc < 4; ++fc) {
        int col = w * 64 + fc * 16 + l15;
        #pragma unroll
        for (int i = 0; i < 4; ++i) {
          int r = fr * 16 + lg * 4 + i;
          float o = fmaxf(acc[fr][fc][i] + b1v[fc], 0.f);
          outH[(size_t)(rowBase + r) * 256 + col] = f2bf(o);
        }
      }
  }
}

// ---------------- readout stage 2 (MFMA): out = relu(h1 @ W2 + b2) . W3 + b3 -----------------
__global__ __launch_bounds__(256) void k_ro2(
    const unsigned short* __restrict__ inH,   // rows x 256 bf16
    float* __restrict__ out, int nTiles,
    const float* __restrict__ W2, const float* __restrict__ b2,
    const float* __restrict__ W3, const float* __restrict__ b3)
{
  __shared__ char WT[128 * 512];   // [128 n][256 k] bf16 swizzled, 64 KB
  __shared__ char sA[16 * 512];    // 16 rows x 256 bf16, 8 KB
  __shared__ float red[16][4];
  const int t = threadIdx.x;
  stageWT(W2, WT, 256, 128, 5);
  const int w   = t >> 6;          // wave -> cols w*32 .. w*32+31
  const int l   = t & 63;
  const int l15 = l & 15;
  const int lg  = l >> 4;
  float b2v[2], w3v[2];
  #pragma unroll
  for (int fc = 0; fc < 2; ++fc) {
    int col = w * 32 + fc * 16 + l15;
    b2v[fc] = b2[col];
    w3v[fc] = W3[col];
  }
  const float b3v = b3[0];
  __syncthreads();

  for (int tile = blockIdx.x; tile < nTiles; tile += gridDim.x) {
    const int rowBase = tile << 4;
    // stage 16 rows x 512 B (bf16 copy, swizzled)
    for (int s = t; s < 512; s += 256) {
      int row = s >> 5, off = (s & 31) * 16;
      u32x4 v = *(const u32x4*)((const char*)inH + (size_t)(rowBase + row) * 512 + off);
      *(u32x4*)(sA + ((row * 512 + off) ^ ((row & 7) << 4))) = v;
    }
    __syncthreads();
    f32x4 acc[2];
    acc[0] = (f32x4){0.f, 0.f, 0.f, 0.f};
    acc[1] = (f32x4){0.f, 0.f, 0.f, 0.f};
    #pragma unroll
    for (int ks = 0; ks < 8; ++ks) {
      int kb = ks * 64 + lg * 16;
      bf16x8 a  = ldsFrag(sA, l15, kb, 512);
      bf16x8 b0 = ldsFrag(WT, w * 32 + l15,      kb, 512);
      bf16x8 b1 = ldsFrag(WT, w * 32 + 16 + l15, kb, 512);
      acc[0] = MFMA(a, b0, acc[0]);
      acc[1] = MFMA(a, b1, acc[1]);
    }
    // h2 = relu(acc + b2); partial dot with W3; reduce over 16-lane group
    #pragma unroll
    for (int i = 0; i < 4; ++i) {
      float p = fmaxf(acc[0][i] + b2v[0], 0.f) * w3v[0]
              + fmaxf(acc[1][i] + b2v[1], 0.f) * w3v[1];
      p += __shfl_xor(p, 1);
      p += __shfl_xor(p, 2);
      p += __shfl_xor(p, 4);
      p += __shfl_xor(p, 8);
      if (l15 == 0) red[lg * 4 + i][w] = p;
    }
    __syncthreads();
    if (t < 16) out[rowBase + t] = red[t][0] + red[t][1] + red[t][2] + red[t][3] + b3v;
    __syncthreads();   // red + sA free for next tile
  }
}

extern "C" void kernel_launch(void* const* d_in, const int* in_sizes, int n_in,
                              void* d_out, int out_size, void* d_ws, size_t ws_size,
                              hipStream_t stream)
{
  const float* x1     = (const float*)d_in[0];
  const float* x2     = (const float*)d_in[1];
  const float* Ac     = (const float*)d_in[2];
  const int*   edge   = (const int*)d_in[3];
  const float* node_W = (const float*)d_in[4];
  const float* node_b = (const float*)d_in[5];
  const float* mlp_W  = (const float*)d_in[6];
  const float* mlp_b  = (const float*)d_in[7];
  const float* egL_W  = (const float*)d_in[8];
  const float* egL_b  = (const float*)d_in[9];
  const float* nro_W1 = (const float*)d_in[10];
  const float* nro_b1 = (const float*)d_in[11];
  const float* nro_W2 = (const float*)d_in[12];
  const float* nro_b2 = (const float*)d_in[13];
  const float* nro_W3 = (const float*)d_in[14];
  const float* nro_b3 = (const float*)d_in[15];
  const float* ero_W1 = (const float*)d_in[16];
  const float* ero_b1 = (const float*)d_in[17];
  const float* ero_W2 = (const float*)d_in[18];
  const float* ero_b2 = (const float*)d_in[19];
  const float* ero_W3 = (const float*)d_in[20];
  const float* ero_b3 = (const float*)d_in[21];
  float* out = (float*)d_out;

  const size_t xnElems = (size_t)NB * NT * 2 * ND;       // 8,388,608
  const size_t xeElems = (size_t)NB * NM * 4 * ND;       // 134,217,728
  if (ws_size < (xnElems * 2 + xeElems) * sizeof(float)) return;

  float* xn  = (float*)d_ws;
  float* upd = xn + xnElems;
  float* xe  = upd + xnElems;

  hipMemcpyAsync(xn, x1, xnElems * sizeof(float), hipMemcpyDeviceToDevice, stream);
  hipMemcpyAsync(xe, x2, xeElems * sizeof(float), hipMemcpyDeviceToDevice, stream);

  for (int i = 0; i < 3; ++i) {
    hipMemsetAsync(upd, 0, xnElems * sizeof(float), stream);
    k_scatter<<<65536, 256, 0, stream>>>(xn, Ac, edge, upd, i > 0);
    k_nodelin<<<2048, 256, 0, stream>>>(xn, upd, node_W + i * ND * ND, node_b + i * ND, i > 0);
    k_edge_mfma<<<2048, 256, 0, stream>>>(xn, xe, edge,
                                          mlp_W + i * ND * ND, mlp_b + i * ND,
                                          egL_W + i * ND * ND, egL_b + i * ND, i < 2);
  }
  // node readout: in-place xn (f32 128/row) -> h1 (bf16 256/row), then reduce
  k_ro1<<<2048, 256, 0, stream>>>(xn, (unsigned short*)xn, (NB * NT * 2) / 32,
                                  nro_W1, nro_b1);
  k_ro2<<<2048, 256, 0, stream>>>((const unsigned short*)xn, out, (NB * NT * 2) / 16,
                                  nro_W2, nro_b2, nro_W3, nro_b3);
  // edge readout
  k_ro1<<<2048, 256, 0, stream>>>(xe, (unsigned short*)xe, (NB * NM * 4) / 32,
                                  ero_W1, ero_b1);
  k_ro2<<<2048, 256, 0, stream>>>((const unsigned short*)xe, out + NB * NT * 2,
                                  (NB * NM * 4) / 16,
                                  ero_W2, ero_b2, ero_W3, ero_b3);
}

// Round 3
// 2595.402 us; speedup vs baseline: 3.9704x; 1.9242x over previous
//
#include <hip/hip_runtime.h>

#define NB 8
#define NT 4096
#define NM 32768
#define ND 128

typedef __attribute__((ext_vector_type(8))) short bf16x8;
typedef __attribute__((ext_vector_type(4))) float f32x4;
typedef __attribute__((ext_vector_type(4))) unsigned int u32x4;

#define MFMA(a,b,c) __builtin_amdgcn_mfma_f32_16x16x32_bf16(a,b,c,0,0,0)

// ---- bf16 helpers (RNE) ----
__device__ __forceinline__ unsigned short f2bf(float x) {
  unsigned u = __float_as_uint(x);
  u += 0x7FFFu + ((u >> 16) & 1u);
  return (unsigned short)(u >> 16);
}
__device__ __forceinline__ float bf2f(unsigned short h) {
  return __uint_as_float(((unsigned)h) << 16);
}

// XOR-swizzled LDS fragment read: 8 consecutive bf16 at (row, kByte)
__device__ __forceinline__ bf16x8 ldsFrag(const char* lds, int row, int kByte, int rowStride) {
  return *(const bf16x8*)(lds + ((row * rowStride + kByte) ^ ((row & 7) << 4)));
}

// Stage W[K][N] (f32, row-major) -> LDS WT[N][K] bf16, XOR-swizzled rows.
__device__ __forceinline__ void stageWT(const float* __restrict__ W, char* lds,
                                        int K, int N, int khShift) {
  const int khn = 1 << khShift;
  const int rowStride = K * 2;
  for (int i = threadIdx.x; i < (N << khShift); i += 256) {
    int n = i >> khShift, kh = i & (khn - 1);
    int k0 = kh << 3;
    unsigned short tmp[8];
    #pragma unroll
    for (int j = 0; j < 8; ++j) tmp[j] = f2bf(W[(k0 + j) * N + n]);
    *(u32x4*)(lds + ((n * rowStride + k0 * 2) ^ ((n & 7) << 4))) = *(u32x4*)tmp;
  }
}

// ================= CSR build (edges constant across layers; deterministic) =================
__global__ __launch_bounds__(256) void k_csr_count(const int* __restrict__ edge, int* deg) {
  int m = blockIdx.x * 256 + threadIdx.x;
  if (m < NM) atomicAdd(&deg[edge[m]], 1);
}
__global__ __launch_bounds__(64) void k_csr_scan(const int* __restrict__ deg,
                                                 int* __restrict__ off, int* __restrict__ cursor) {
  __shared__ int partial[64];
  int t = threadIdx.x;
  int base = t * 64;
  int sum = 0;
  for (int i = 0; i < 64; ++i) sum += deg[base + i];
  partial[t] = sum;
  __syncthreads();
  if (t == 0) {
    int run = 0;
    for (int i = 0; i < 64; ++i) { int v = partial[i]; partial[i] = run; run += v; }
  }
  __syncthreads();
  int run = partial[t];
  for (int i = 0; i < 64; ++i) {
    off[base + i] = run; cursor[base + i] = run;
    run += deg[base + i];
  }
  if (t == 63) off[NT] = NM;
}
__global__ __launch_bounds__(256) void k_csr_fill(const int* __restrict__ edge,
                                                  int* cursor, int* __restrict__ csr) {
  int m = blockIdx.x * 256 + threadIdx.x;
  if (m < NM) { int pos = atomicAdd(&cursor[edge[m]], 1); csr[pos] = m; }
}
__global__ __launch_bounds__(256) void k_csr_sort(const int* __restrict__ off, int* __restrict__ csr) {
  int n = blockIdx.x * 256 + threadIdx.x;
  if (n < NT) {
    int s = off[n], e = off[n + 1];
    for (int i = s + 1; i < e; ++i) {
      int v = csr[i]; int j = i - 1;
      while (j >= s && csr[j] > v) { csr[j + 1] = csr[j]; --j; }
      csr[j + 1] = v;
    }
  }
}

// ====== fused node layer: xnOut = (relu?(xnIn) + gatherCSR(xnIn)) @ W + b  (f32 GEMM) ======
__global__ __launch_bounds__(256) void k_node(
    const float* __restrict__ xnIn, float* __restrict__ xnOut,
    const float* __restrict__ A, const int* __restrict__ edge,
    const int* __restrict__ off, const int* __restrict__ csr,
    const float* __restrict__ W, const float* __restrict__ bias, int doReluIn)
{
  __shared__ float Ws[ND * ND];     // 64 KB
  __shared__ float xs[32][ND];      // 16 KB  -> 80 KB, 2 blocks/CU
  const int t = threadIdx.x;
  for (int i = t; i < ND * ND; i += 256) Ws[i] = W[i];

  const int rowBase = blockIdx.x << 5;
  // ---- gather phase: 8 threads per row, 16 f32 accumulators each ----
  {
    const int r  = t >> 3;            // 0..31
    const int c0 = (t & 7) << 4;      // col block of 16
    const int grow = rowBase + r;
    const int ch   = grow & 1;
    const int node = (grow >> 1) & (NT - 1);
    const int b    = grow >> 13;      // / (NT*2)
    f32x4 acc[4];
    {
      const float4* xr = (const float4*)(xnIn + (size_t)grow * ND + c0);
      #pragma unroll
      for (int q = 0; q < 4; ++q) {
        float4 v = xr[q];
        if (doReluIn) {
          v.x = fmaxf(v.x, 0.f); v.y = fmaxf(v.y, 0.f);
          v.z = fmaxf(v.z, 0.f); v.w = fmaxf(v.w, 0.f);
        }
        acc[q] = (f32x4){v.x, v.y, v.z, v.w};
      }
    }
    const int s = off[node], e = off[node + 1];
    for (int p = s; p < e; ++p) {
      int m = csr[p];
      float a = A[b * NM + m];
      int e1 = edge[NM + m];
      const float4* src = (const float4*)(xnIn + (size_t)(((b * NT + e1) << 1) + ch) * ND + c0);
      #pragma unroll
      for (int q = 0; q < 4; ++q) {
        float4 v = src[q];
        if (doReluIn) {
          v.x = fmaxf(v.x, 0.f); v.y = fmaxf(v.y, 0.f);
          v.z = fmaxf(v.z, 0.f); v.w = fmaxf(v.w, 0.f);
        }
        acc[q][0] = fmaf(a, v.x, acc[q][0]);
        acc[q][1] = fmaf(a, v.y, acc[q][1]);
        acc[q][2] = fmaf(a, v.z, acc[q][2]);
        acc[q][3] = fmaf(a, v.w, acc[q][3]);
      }
    }
    #pragma unroll
    for (int q = 0; q < 4; ++q) *(f32x4*)&xs[r][c0 + q * 4] = acc[q];
  }
  const int c4 = (t & 31) << 2;
  const int rg = t >> 5;
  float4 bv = *(const float4*)(bias + c4);
  __syncthreads();
  // ---- GEMM phase (f32 register tile) ----
  float acc[4][4];
  #pragma unroll
  for (int r = 0; r < 4; ++r)
    #pragma unroll
    for (int c = 0; c < 4; ++c) acc[r][c] = 0.f;
  for (int k = 0; k < ND; k += 4) {
    float4 sv[4];
    #pragma unroll
    for (int r = 0; r < 4; ++r) sv[r] = *(const float4*)&xs[(rg << 2) + r][k];
    #pragma unroll
    for (int j = 0; j < 4; ++j) {
      float4 w = *(const float4*)&Ws[(k + j) * ND + c4];
      #pragma unroll
      for (int r = 0; r < 4; ++r) {
        float s = ((const float*)&sv[r])[j];
        acc[r][0] += s * w.x; acc[r][1] += s * w.y;
        acc[r][2] += s * w.z; acc[r][3] += s * w.w;
      }
    }
  }
  #pragma unroll
  for (int r = 0; r < 4; ++r) {
    float4 o;
    o.x = acc[r][0] + bv.x; o.y = acc[r][1] + bv.y;
    o.z = acc[r][2] + bv.z; o.w = acc[r][3] + bv.w;
    *(float4*)&xnOut[(size_t)(rowBase + (rg << 2) + r) * ND + c4] = o;
  }
}

// ---------------- edge layer (MFMA): xe = relu?((xe + (ei+ej)@Wm + bm) @ We + be) ------------
__global__ __launch_bounds__(256) void k_edge_mfma(
    const float* __restrict__ xn, float* xe,
    const int* __restrict__ edge,
    const float* __restrict__ Wm, const float* __restrict__ bm,
    const float* __restrict__ We, const float* __restrict__ be,
    int doReluOut)
{
  __shared__ char WmT[128 * 256];
  __shared__ char WeT[128 * 256];
  __shared__ char sA[32 * 256];
  const int t = threadIdx.x;
  stageWT(Wm, WmT, 128, 128, 4);
  stageWT(We, WeT, 128, 128, 4);
  const int w   = t >> 6;
  const int l   = t & 63;
  const int l15 = l & 15;
  const int lg  = l >> 4;
  float bmv[2], bev[2];
  #pragma unroll
  for (int fc = 0; fc < 2; ++fc) {
    int col = w * 32 + fc * 16 + l15;
    bmv[fc] = bm[col];
    bev[fc] = be[col];
  }
  const int srow = t >> 3;
  __syncthreads();

  const int nTiles = (NB * NM * 4) / 32;
  for (int tile = blockIdx.x; tile < nTiles; tile += gridDim.x) {
    const int rowBase = tile << 5;
    {
      int grow = rowBase + srow;
      int cch = grow & 3;
      int m = (grow >> 2) & (NM - 1);
      int b = grow >> 17;
      int e0 = edge[m], e1 = edge[NM + m];
      const float* p0 = xn + (size_t)((b * NT + e0) * 2 + (cch >> 1)) * ND;
      const float* p1 = xn + (size_t)((b * NT + e1) * 2 + (cch & 1)) * ND;
      #pragma unroll
      for (int hh = 0; hh < 2; ++hh) {
        int h = (t & 7) + hh * 8;
        float4 a0 = *(const float4*)(p0 + h * 8);
        float4 a1 = *(const float4*)(p0 + h * 8 + 4);
        float4 c0 = *(const float4*)(p1 + h * 8);
        float4 c1 = *(const float4*)(p1 + h * 8 + 4);
        unsigned short tmp[8];
        tmp[0] = f2bf(a0.x + c0.x); tmp[1] = f2bf(a0.y + c0.y);
        tmp[2] = f2bf(a0.z + c0.z); tmp[3] = f2bf(a0.w + c0.w);
        tmp[4] = f2bf(a1.x + c1.x); tmp[5] = f2bf(a1.y + c1.y);
        tmp[6] = f2bf(a1.z + c1.z); tmp[7] = f2bf(a1.w + c1.w);
        *(u32x4*)(sA + ((srow * 256 + h * 16) ^ ((srow & 7) << 4))) = *(u32x4*)tmp;
      }
    }
    __syncthreads();
    f32x4 acc[2][2];
    #pragma unroll
    for (int fr = 0; fr < 2; ++fr)
      #pragma unroll
      for (int fc = 0; fc < 2; ++fc) acc[fr][fc] = (f32x4){0.f, 0.f, 0.f, 0.f};
    #pragma unroll
    for (int ks = 0; ks < 4; ++ks) {
      int kb = ks * 64 + lg * 16;
      bf16x8 a0 = ldsFrag(sA, l15,      kb, 256);
      bf16x8 a1 = ldsFrag(sA, 16 + l15, kb, 256);
      bf16x8 b0 = ldsFrag(WmT, w * 32 + l15,      kb, 256);
      bf16x8 b1 = ldsFrag(WmT, w * 32 + 16 + l15, kb, 256);
      acc[0][0] = MFMA(a0, b0, acc[0][0]);
      acc[0][1] = MFMA(a0, b1, acc[0][1]);
      acc[1][0] = MFMA(a1, b0, acc[1][0]);
      acc[1][1] = MFMA(a1, b1, acc[1][1]);
    }
    __syncthreads();
    #pragma unroll
    for (int fr = 0; fr < 2; ++fr)
      #pragma unroll
      for (int fc = 0; fc < 2; ++fc) {
        int col = w * 32 + fc * 16 + l15;
        #pragma unroll
        for (int i = 0; i < 4; ++i) {
          int r = fr * 16 + lg * 4 + i;
          float v = xe[(size_t)(rowBase + r) * ND + col] + acc[fr][fc][i] + bmv[fc];
          *(unsigned short*)(sA + ((r * 256 + col * 2) ^ ((r & 7) << 4))) = f2bf(v);
        }
      }
    __syncthreads();
    f32x4 acc2[2][2];
    #pragma unroll
    for (int fr = 0; fr < 2; ++fr)
      #pragma unroll
      for (int fc = 0; fc < 2; ++fc) acc2[fr][fc] = (f32x4){0.f, 0.f, 0.f, 0.f};
    #pragma unroll
    for (int ks = 0; ks < 4; ++ks) {
      int kb = ks * 64 + lg * 16;
      bf16x8 a0 = ldsFrag(sA, l15,      kb, 256);
      bf16x8 a1 = ldsFrag(sA, 16 + l15, kb, 256);
      bf16x8 b0 = ldsFrag(WeT, w * 32 + l15,      kb, 256);
      bf16x8 b1 = ldsFrag(WeT, w * 32 + 16 + l15, kb, 256);
      acc2[0][0] = MFMA(a0, b0, acc2[0][0]);
      acc2[0][1] = MFMA(a0, b1, acc2[0][1]);
      acc2[1][0] = MFMA(a1, b0, acc2[1][0]);
      acc2[1][1] = MFMA(a1, b1, acc2[1][1]);
    }
    __syncthreads();
    #pragma unroll
    for (int fr = 0; fr < 2; ++fr)
      #pragma unroll
      for (int fc = 0; fc < 2; ++fc) {
        int col = w * 32 + fc * 16 + l15;
        #pragma unroll
        for (int i = 0; i < 4; ++i) {
          int r = fr * 16 + lg * 4 + i;
          float o = acc2[fr][fc][i] + bev[fc];
          if (doReluOut) o = fmaxf(o, 0.f);
          xe[(size_t)(rowBase + r) * ND + col] = o;
        }
      }
  }
}

// ---------------- readout stage 1 (MFMA): h1 = relu(x @ W1 + b1), bf16 in-place --------------
__global__ __launch_bounds__(256) void k_ro1(
    const float* inF, unsigned short* outH, int nTiles,
    const float* __restrict__ W1, const float* __restrict__ b1)
{
  __shared__ char WT[256 * 256];
  __shared__ char sA[32 * 256];
  const int t = threadIdx.x;
  stageWT(W1, WT, 128, 256, 4);
  const int w   = t >> 6;
  const int l   = t & 63;
  const int l15 = l & 15;
  const int lg  = l >> 4;
  float b1v[4];
  #pragma unroll
  for (int fc = 0; fc < 4; ++fc) b1v[fc] = b1[w * 64 + fc * 16 + l15];
  const int srow = t >> 3;
  __syncthreads();

  for (int tile = blockIdx.x; tile < nTiles; tile += gridDim.x) {
    const int rowBase = tile << 5;
    {
      const float* p0 = inF + (size_t)(rowBase + srow) * ND;
      #pragma unroll
      for (int hh = 0; hh < 2; ++hh) {
        int h = (t & 7) + hh * 8;
        float4 a0 = *(const float4*)(p0 + h * 8);
        float4 a1 = *(const float4*)(p0 + h * 8 + 4);
        unsigned short tmp[8];
        tmp[0] = f2bf(a0.x); tmp[1] = f2bf(a0.y);
        tmp[2] = f2bf(a0.z); tmp[3] = f2bf(a0.w);
        tmp[4] = f2bf(a1.x); tmp[5] = f2bf(a1.y);
        tmp[6] = f2bf(a1.z); tmp[7] = f2bf(a1.w);
        *(u32x4*)(sA + ((srow * 256 + h * 16) ^ ((srow & 7) << 4))) = *(u32x4*)tmp;
      }
    }
    __syncthreads();
    f32x4 acc[2][4];
    #pragma unroll
    for (int fr = 0; fr < 2; ++fr)
      #pragma unroll
      for (int fc = 0; fc < 4; ++fc) acc[fr][fc] = (f32x4){0.f, 0.f, 0.f, 0.f};
    #pragma unroll
    for (int ks = 0; ks < 4; ++ks) {
      int kb = ks * 64 + lg * 16;
      bf16x8 a0 = ldsFrag(sA, l15,      kb, 256);
      bf16x8 a1 = ldsFrag(sA, 16 + l15, kb, 256);
      #pragma unroll
      for (int fc = 0; fc < 4; ++fc) {
        bf16x8 bfr = ldsFrag(WT, w * 64 + fc * 16 + l15, kb, 256);
        acc[0][fc] = MFMA(a0, bfr, acc[0][fc]);
        acc[1][fc] = MFMA(a1, bfr, acc[1][fc]);
      }
    }
    __syncthreads();
    #pragma unroll
    for (int fr = 0; fr < 2; ++fr)
      #pragma unroll
      for (int fc = 0; fc < 4; ++fc) {
        int col = w * 64 + fc * 16 + l15;
        #pragma unroll
        for (int i = 0; i < 4; ++i) {
          int r = fr * 16 + lg * 4 + i;
          float o = fmaxf(acc[fr][fc][i] + b1v[fc], 0.f);
          outH[(size_t)(rowBase + r) * 256 + col] = f2bf(o);
        }
      }
  }
}

// ---------------- readout stage 2 (MFMA): out = relu(h1 @ W2 + b2) . W3 + b3 -----------------
__global__ __launch_bounds__(256) void k_ro2(
    const unsigned short* __restrict__ inH,
    float* __restrict__ out, int nTiles,
    const float* __restrict__ W2, const float* __restrict__ b2,
    const float* __restrict__ W3, const float* __restrict__ b3)
{
  __shared__ char WT[128 * 512];
  __shared__ char sA[16 * 512];
  __shared__ float red[16][4];
  const int t = threadIdx.x;
  stageWT(W2, WT, 256, 128, 5);
  const int w   = t >> 6;
  const int l   = t & 63;
  const int l15 = l & 15;
  const int lg  = l >> 4;
  float b2v[2], w3v[2];
  #pragma unroll
  for (int fc = 0; fc < 2; ++fc) {
    int col = w * 32 + fc * 16 + l15;
    b2v[fc] = b2[col];
    w3v[fc] = W3[col];
  }
  const float b3v = b3[0];
  __syncthreads();

  for (int tile = blockIdx.x; tile < nTiles; tile += gridDim.x) {
    const int rowBase = tile << 4;
    for (int s = t; s < 512; s += 256) {
      int row = s >> 5, off = (s & 31) * 16;
      u32x4 v = *(const u32x4*)((const char*)inH + (size_t)(rowBase + row) * 512 + off);
      *(u32x4*)(sA + ((row * 512 + off) ^ ((row & 7) << 4))) = v;
    }
    __syncthreads();
    f32x4 acc[2];
    acc[0] = (f32x4){0.f, 0.f, 0.f, 0.f};
    acc[1] = (f32x4){0.f, 0.f, 0.f, 0.f};
    #pragma unroll
    for (int ks = 0; ks < 8; ++ks) {
      int kb = ks * 64 + lg * 16;
      bf16x8 a  = ldsFrag(sA, l15, kb, 512);
      bf16x8 b0 = ldsFrag(WT, w * 32 + l15,      kb, 512);
      bf16x8 b1 = ldsFrag(WT, w * 32 + 16 + l15, kb, 512);
      acc[0] = MFMA(a, b0, acc[0]);
      acc[1] = MFMA(a, b1, acc[1]);
    }
    #pragma unroll
    for (int i = 0; i < 4; ++i) {
      float p = fmaxf(acc[0][i] + b2v[0], 0.f) * w3v[0]
              + fmaxf(acc[1][i] + b2v[1], 0.f) * w3v[1];
      p += __shfl_xor(p, 1);
      p += __shfl_xor(p, 2);
      p += __shfl_xor(p, 4);
      p += __shfl_xor(p, 8);
      if (l15 == 0) red[lg * 4 + i][w] = p;
    }
    __syncthreads();
    if (t < 16) out[rowBase + t] = red[t][0] + red[t][1] + red[t][2] + red[t][3] + b3v;
    __syncthreads();
  }
}

extern "C" void kernel_launch(void* const* d_in, const int* in_sizes, int n_in,
                              void* d_out, int out_size, void* d_ws, size_t ws_size,
                              hipStream_t stream)
{
  const float* x1     = (const float*)d_in[0];
  const float* x2     = (const float*)d_in[1];
  const float* Ac     = (const float*)d_in[2];
  const int*   edge   = (const int*)d_in[3];
  const float* node_W = (const float*)d_in[4];
  const float* node_b = (const float*)d_in[5];
  const float* mlp_W  = (const float*)d_in[6];
  const float* mlp_b  = (const float*)d_in[7];
  const float* egL_W  = (const float*)d_in[8];
  const float* egL_b  = (const float*)d_in[9];
  const float* nro_W1 = (const float*)d_in[10];
  const float* nro_b1 = (const float*)d_in[11];
  const float* nro_W2 = (const float*)d_in[12];
  const float* nro_b2 = (const float*)d_in[13];
  const float* nro_W3 = (const float*)d_in[14];
  const float* nro_b3 = (const float*)d_in[15];
  const float* ero_W1 = (const float*)d_in[16];
  const float* ero_b1 = (const float*)d_in[17];
  const float* ero_W2 = (const float*)d_in[18];
  const float* ero_b2 = (const float*)d_in[19];
  const float* ero_W3 = (const float*)d_in[20];
  const float* ero_b3 = (const float*)d_in[21];
  float* out = (float*)d_out;

  const size_t xnElems = (size_t)NB * NT * 2 * ND;       // 8,388,608
  const size_t xeElems = (size_t)NB * NM * 4 * ND;       // 134,217,728
  if (ws_size < (xnElems * 2 + xeElems) * sizeof(float)) return;

  float* xnA = (float*)d_ws;
  float* xnB = xnA + xnElems;
  float* xe  = xnB + xnElems;

  // CSR scratch lives in d_out (readouts overwrite it at the end)
  int* deg    = (int*)d_out;          // 4096
  int* off    = deg + NT;             // 4097
  int* cursor = off + NT + 1;         // 4096
  int* csr    = cursor + NT;          // 32768   (total 180 KB << out bytes)

  hipMemcpyAsync(xnA, x1, xnElems * sizeof(float), hipMemcpyDeviceToDevice, stream);
  hipMemcpyAsync(xe,  x2, xeElems * sizeof(float), hipMemcpyDeviceToDevice, stream);
  hipMemsetAsync(deg, 0, NT * sizeof(int), stream);
  k_csr_count<<<NM / 256, 256, 0, stream>>>(edge, deg);
  k_csr_scan<<<1, 64, 0, stream>>>(deg, off, cursor);
  k_csr_fill<<<NM / 256, 256, 0, stream>>>(edge, cursor, csr);
  k_csr_sort<<<NT / 256, 256, 0, stream>>>(off, csr);

  float* cur = xnA;
  float* nxt = xnB;
  for (int i = 0; i < 3; ++i) {
    k_node<<<2048, 256, 0, stream>>>(cur, nxt, Ac, edge, off, csr,
                                     node_W + i * ND * ND, node_b + i * ND, i > 0);
    k_edge_mfma<<<2048, 256, 0, stream>>>(nxt, xe, edge,
                                          mlp_W + i * ND * ND, mlp_b + i * ND,
                                          egL_W + i * ND * ND, egL_b + i * ND, i < 2);
    float* tmp = cur; cur = nxt; nxt = tmp;
  }
  // after 3 swaps: final xn is in `cur`
  k_ro1<<<2048, 256, 0, stream>>>(cur, (unsigned short*)cur, (NB * NT * 2) / 32,
                                  nro_W1, nro_b1);
  k_ro2<<<2048, 256, 0, stream>>>((const unsigned short*)cur, out, (NB * NT * 2) / 16,
                                  nro_W2, nro_b2, nro_W3, nro_b3);
  k_ro1<<<2048, 256, 0, stream>>>(xe, (unsigned short*)xe, (NB * NM * 4) / 32,
                                  ero_W1, ero_b1);
  k_ro2<<<2048, 256, 0, stream>>>((const unsigned short*)xe, out + NB * NT * 2,
                                  (NB * NM * 4) / 16,
                                  ero_W2, ero_b2, ero_W3, ero_b3);
}

// Round 4
// 2589.992 us; speedup vs baseline: 3.9787x; 1.0021x over previous
//
#include <hip/hip_runtime.h>

#define NB 8
#define NT 4096
#define NM 32768
#define ND 128

typedef __attribute__((ext_vector_type(8))) short bf16x8;
typedef __attribute__((ext_vector_type(4))) float f32x4;
typedef __attribute__((ext_vector_type(4))) unsigned int u32x4;

#define MFMA(a,b,c) __builtin_amdgcn_mfma_f32_16x16x32_bf16(a,b,c,0,0,0)

// ---- bf16 helpers (RNE) ----
__device__ __forceinline__ unsigned short f2bf(float x) {
  unsigned u = __float_as_uint(x);
  u += 0x7FFFu + ((u >> 16) & 1u);
  return (unsigned short)(u >> 16);
}

// XOR-swizzled LDS fragment read: 8 consecutive bf16 at (row, kByte)
__device__ __forceinline__ bf16x8 ldsFrag(const char* lds, int row, int kByte, int rowStride) {
  return *(const bf16x8*)(lds + ((row * rowStride + kByte) ^ ((row & 7) << 4)));
}

// Stage W[K][N] (f32, row-major) -> LDS WT[N][K] bf16, XOR-swizzled rows.
__device__ __forceinline__ void stageWT(const float* __restrict__ W, char* lds,
                                        int K, int N, int khShift) {
  const int khn = 1 << khShift;
  const int rowStride = K * 2;
  for (int i = threadIdx.x; i < (N << khShift); i += 256) {
    int n = i >> khShift, kh = i & (khn - 1);
    int k0 = kh << 3;
    unsigned short tmp[8];
    #pragma unroll
    for (int j = 0; j < 8; ++j) tmp[j] = f2bf(W[(k0 + j) * N + n]);
    *(u32x4*)(lds + ((n * rowStride + k0 * 2) ^ ((n & 7) << 4))) = *(u32x4*)tmp;
  }
}

// ================= CSR build (edges constant across layers; deterministic) =================
__global__ __launch_bounds__(256) void k_csr_count(const int* __restrict__ edge, int* deg) {
  int m = blockIdx.x * 256 + threadIdx.x;
  if (m < NM) atomicAdd(&deg[edge[m]], 1);
}
__global__ __launch_bounds__(64) void k_csr_scan(const int* __restrict__ deg,
                                                 int* __restrict__ off, int* __restrict__ cursor) {
  __shared__ int partial[64];
  int t = threadIdx.x;
  int base = t * 64;
  int sum = 0;
  for (int i = 0; i < 64; ++i) sum += deg[base + i];
  partial[t] = sum;
  __syncthreads();
  if (t == 0) {
    int run = 0;
    for (int i = 0; i < 64; ++i) { int v = partial[i]; partial[i] = run; run += v; }
  }
  __syncthreads();
  int run = partial[t];
  for (int i = 0; i < 64; ++i) {
    off[base + i] = run; cursor[base + i] = run;
    run += deg[base + i];
  }
  if (t == 63) off[NT] = NM;
}
__global__ __launch_bounds__(256) void k_csr_fill(const int* __restrict__ edge,
                                                  int* cursor, int* __restrict__ csr) {
  int m = blockIdx.x * 256 + threadIdx.x;
  if (m < NM) { int pos = atomicAdd(&cursor[edge[m]], 1); csr[pos] = m; }
}
__global__ __launch_bounds__(256) void k_csr_sort(const int* __restrict__ off, int* __restrict__ csr) {
  int n = blockIdx.x * 256 + threadIdx.x;
  if (n < NT) {
    int s = off[n], e = off[n + 1];
    for (int i = s + 1; i < e; ++i) {
      int v = csr[i]; int j = i - 1;
      while (j >= s && csr[j] > v) { csr[j + 1] = csr[j]; --j; }
      csr[j + 1] = v;
    }
  }
}

// ====== fused node layer: xnOut = (relu?(xnIn) + gatherCSR(xnIn)) @ W + b  (f32 GEMM) ======
__global__ __launch_bounds__(256) void k_node(
    const float* __restrict__ xnIn, float* __restrict__ xnOut,
    const float* __restrict__ A, const int* __restrict__ edge,
    const int* __restrict__ off, const int* __restrict__ csr,
    const float* __restrict__ W, const float* __restrict__ bias, int doReluIn)
{
  __shared__ float Ws[ND * ND];     // 64 KB
  __shared__ float xs[32][ND];      // 16 KB  -> 80 KB, 2 blocks/CU
  const int t = threadIdx.x;
  for (int i = t; i < ND * ND; i += 256) Ws[i] = W[i];

  const int rowBase = blockIdx.x << 5;
  // ---- gather phase: 8 threads per row, 16 f32 accumulators each ----
  {
    const int r  = t >> 3;
    const int c0 = (t & 7) << 4;
    const int grow = rowBase + r;
    const int ch   = grow & 1;
    const int node = (grow >> 1) & (NT - 1);
    const int b    = grow >> 13;
    f32x4 acc[4];
    {
      const float4* xr = (const float4*)(xnIn + (size_t)grow * ND + c0);
      #pragma unroll
      for (int q = 0; q < 4; ++q) {
        float4 v = xr[q];
        if (doReluIn) {
          v.x = fmaxf(v.x, 0.f); v.y = fmaxf(v.y, 0.f);
          v.z = fmaxf(v.z, 0.f); v.w = fmaxf(v.w, 0.f);
        }
        acc[q] = (f32x4){v.x, v.y, v.z, v.w};
      }
    }
    const int s = off[node], e = off[node + 1];
    for (int p = s; p < e; ++p) {
      int m = csr[p];
      float a = A[b * NM + m];
      int e1 = edge[NM + m];
      const float4* src = (const float4*)(xnIn + (size_t)(((b * NT + e1) << 1) + ch) * ND + c0);
      #pragma unroll
      for (int q = 0; q < 4; ++q) {
        float4 v = src[q];
        if (doReluIn) {
          v.x = fmaxf(v.x, 0.f); v.y = fmaxf(v.y, 0.f);
          v.z = fmaxf(v.z, 0.f); v.w = fmaxf(v.w, 0.f);
        }
        acc[q][0] = fmaf(a, v.x, acc[q][0]);
        acc[q][1] = fmaf(a, v.y, acc[q][1]);
        acc[q][2] = fmaf(a, v.z, acc[q][2]);
        acc[q][3] = fmaf(a, v.w, acc[q][3]);
      }
    }
    #pragma unroll
    for (int q = 0; q < 4; ++q) *(f32x4*)&xs[r][c0 + q * 4] = acc[q];
  }
  const int c4 = (t & 31) << 2;
  const int rg = t >> 5;
  float4 bv = *(const float4*)(bias + c4);
  __syncthreads();
  float acc[4][4];
  #pragma unroll
  for (int r = 0; r < 4; ++r)
    #pragma unroll
    for (int c = 0; c < 4; ++c) acc[r][c] = 0.f;
  for (int k = 0; k < ND; k += 4) {
    float4 sv[4];
    #pragma unroll
    for (int r = 0; r < 4; ++r) sv[r] = *(const float4*)&xs[(rg << 2) + r][k];
    #pragma unroll
    for (int j = 0; j < 4; ++j) {
      float4 w = *(const float4*)&Ws[(k + j) * ND + c4];
      #pragma unroll
      for (int r = 0; r < 4; ++r) {
        float s = ((const float*)&sv[r])[j];
        acc[r][0] += s * w.x; acc[r][1] += s * w.y;
        acc[r][2] += s * w.z; acc[r][3] += s * w.w;
      }
    }
  }
  #pragma unroll
  for (int r = 0; r < 4; ++r) {
    float4 o;
    o.x = acc[r][0] + bv.x; o.y = acc[r][1] + bv.y;
    o.z = acc[r][2] + bv.z; o.w = acc[r][3] + bv.w;
    *(float4*)&xnOut[(size_t)(rowBase + (rg << 2) + r) * ND + c4] = o;
  }
}

// ------- edge layer (MFMA, 64-row tiles): xeOut = relu?((xeIn + (ei+ej)@Wm + bm)@We + be) ----
__global__ __launch_bounds__(256) void k_edge_mfma(
    const float* __restrict__ xn, const float* __restrict__ xeIn, float* xeOut,
    const int* __restrict__ edge,
    const float* __restrict__ Wm, const float* __restrict__ bm,
    const float* __restrict__ We, const float* __restrict__ be,
    int doReluOut)
{
  __shared__ char WmT[128 * 256];   // 32 KB
  __shared__ char WeT[128 * 256];   // 32 KB
  __shared__ char sA[64 * 256];     // 16 KB -> 80 KB, 2 blocks/CU
  const int t = threadIdx.x;
  stageWT(Wm, WmT, 128, 128, 4);
  stageWT(We, WeT, 128, 128, 4);
  const int w   = t >> 6;
  const int l   = t & 63;
  const int l15 = l & 15;
  const int lg  = l >> 4;
  float bmv[2], bev[2];
  #pragma unroll
  for (int fc = 0; fc < 2; ++fc) {
    int col = w * 32 + fc * 16 + l15;
    bmv[fc] = bm[col];
    bev[fc] = be[col];
  }
  const int srow = t >> 2;          // 64 rows, 4 threads/row
  __syncthreads();

  const int nTiles = (NB * NM * 4) / 64;   // 16384
  for (int tile = blockIdx.x; tile < nTiles; tile += gridDim.x) {
    const int rowBase = tile << 6;
    // ---- stage sA = bf16(xn[e0,ni] + xn[e1,nj])  (64 rows x 128) ----
    {
      int grow = rowBase + srow;
      int cch = grow & 3;
      int m = (grow >> 2) & (NM - 1);
      int b = grow >> 17;
      int e0 = edge[m], e1 = edge[NM + m];
      const float4* p0 = (const float4*)(xn + (size_t)((b * NT + e0) * 2 + (cch >> 1)) * ND);
      const float4* p1 = (const float4*)(xn + (size_t)((b * NT + e1) * 2 + (cch & 1)) * ND);
      #pragma unroll
      for (int hh = 0; hh < 4; ++hh) {
        int h = (t & 3) + hh * 4;          // 16B slot 0..15
        float4 a0 = p0[h * 2], a1 = p0[h * 2 + 1];
        float4 c0 = p1[h * 2], c1 = p1[h * 2 + 1];
        unsigned short tmp[8];
        tmp[0] = f2bf(a0.x + c0.x); tmp[1] = f2bf(a0.y + c0.y);
        tmp[2] = f2bf(a0.z + c0.z); tmp[3] = f2bf(a0.w + c0.w);
        tmp[4] = f2bf(a1.x + c1.x); tmp[5] = f2bf(a1.y + c1.y);
        tmp[6] = f2bf(a1.z + c1.z); tmp[7] = f2bf(a1.w + c1.w);
        *(u32x4*)(sA + ((srow * 256 + h * 16) ^ ((srow & 7) << 4))) = *(u32x4*)tmp;
      }
    }
    __syncthreads();
    // ---- phase A: T = sA @ Wm ----
    f32x4 acc[4][2];
    #pragma unroll
    for (int fr = 0; fr < 4; ++fr)
      #pragma unroll
      for (int fc = 0; fc < 2; ++fc) acc[fr][fc] = (f32x4){0.f, 0.f, 0.f, 0.f};
    #pragma unroll
    for (int ks = 0; ks < 4; ++ks) {
      int kb = ks * 64 + lg * 16;
      bf16x8 b0 = ldsFrag(WmT, w * 32 + l15,      kb, 256);
      bf16x8 b1 = ldsFrag(WmT, w * 32 + 16 + l15, kb, 256);
      #pragma unroll
      for (int fr = 0; fr < 4; ++fr) {
        bf16x8 a = ldsFrag(sA, fr * 16 + l15, kb, 256);
        acc[fr][0] = MFMA(a, b0, acc[fr][0]);
        acc[fr][1] = MFMA(a, b1, acc[fr][1]);
      }
    }
    __syncthreads();
    // ---- v = xeIn + T + bm -> sA (bf16) ----
    #pragma unroll
    for (int fr = 0; fr < 4; ++fr)
      #pragma unroll
      for (int fc = 0; fc < 2; ++fc) {
        int col = w * 32 + fc * 16 + l15;
        #pragma unroll
        for (int i = 0; i < 4; ++i) {
          int r = fr * 16 + lg * 4 + i;
          float v = xeIn[(size_t)(rowBase + r) * ND + col] + acc[fr][fc][i] + bmv[fc];
          *(unsigned short*)(sA + ((r * 256 + col * 2) ^ ((r & 7) << 4))) = f2bf(v);
        }
      }
    __syncthreads();
    // ---- phase B: O = v @ We ----
    #pragma unroll
    for (int fr = 0; fr < 4; ++fr)
      #pragma unroll
      for (int fc = 0; fc < 2; ++fc) acc[fr][fc] = (f32x4){0.f, 0.f, 0.f, 0.f};
    #pragma unroll
    for (int ks = 0; ks < 4; ++ks) {
      int kb = ks * 64 + lg * 16;
      bf16x8 b0 = ldsFrag(WeT, w * 32 + l15,      kb, 256);
      bf16x8 b1 = ldsFrag(WeT, w * 32 + 16 + l15, kb, 256);
      #pragma unroll
      for (int fr = 0; fr < 4; ++fr) {
        bf16x8 a = ldsFrag(sA, fr * 16 + l15, kb, 256);
        acc[fr][0] = MFMA(a, b0, acc[fr][0]);
        acc[fr][1] = MFMA(a, b1, acc[fr][1]);
      }
    }
    __syncthreads();   // sA free for next tile
    // ---- epilogue ----
    #pragma unroll
    for (int fr = 0; fr < 4; ++fr)
      #pragma unroll
      for (int fc = 0; fc < 2; ++fc) {
        int col = w * 32 + fc * 16 + l15;
        #pragma unroll
        for (int i = 0; i < 4; ++i) {
          int r = fr * 16 + lg * 4 + i;
          float o = acc[fr][fc][i] + bev[fc];
          if (doReluOut) o = fmaxf(o, 0.f);
          xeOut[(size_t)(rowBase + r) * ND + col] = o;
        }
      }
  }
}

// ------- readout stage 1 (MFMA, direct-global A): h1 = relu(x @ W1 + b1), bf16 in-place ------
__global__ __launch_bounds__(256) void k_ro1(
    const float* inF,              // rows x 128 f32 (aliases outH)
    unsigned short* outH,          // rows x 256 bf16
    int nTiles,
    const float* __restrict__ W1, const float* __restrict__ b1)
{
  __shared__ char WT[256 * 256];   // 64 KB
  const int t = threadIdx.x;
  stageWT(W1, WT, 128, 256, 4);
  const int w   = t >> 6;
  const int l   = t & 63;
  const int l15 = l & 15;
  const int lg  = l >> 4;
  float b1v[4];
  #pragma unroll
  for (int fc = 0; fc < 4; ++fc) b1v[fc] = b1[w * 64 + fc * 16 + l15];
  __syncthreads();

  for (int tile = blockIdx.x; tile < nTiles; tile += gridDim.x) {
    const int rowBase = tile << 5;
    f32x4 acc[2][4];
    #pragma unroll
    for (int fr = 0; fr < 2; ++fr)
      #pragma unroll
      for (int fc = 0; fc < 4; ++fc) acc[fr][fc] = (f32x4){0.f, 0.f, 0.f, 0.f};
    #pragma unroll
    for (int ks = 0; ks < 4; ++ks) {
      const int kf = ks * 32 + lg * 8;          // f32 element offset
      bf16x8 a[2];
      #pragma unroll
      for (int fr = 0; fr < 2; ++fr) {
        const float4* p = (const float4*)(inF + (size_t)(rowBase + fr * 16 + l15) * ND + kf);
        float4 v0 = p[0], v1 = p[1];
        unsigned short tmp[8];
        tmp[0] = f2bf(v0.x); tmp[1] = f2bf(v0.y); tmp[2] = f2bf(v0.z); tmp[3] = f2bf(v0.w);
        tmp[4] = f2bf(v1.x); tmp[5] = f2bf(v1.y); tmp[6] = f2bf(v1.z); tmp[7] = f2bf(v1.w);
        a[fr] = *(bf16x8*)tmp;
      }
      #pragma unroll
      for (int fc = 0; fc < 4; ++fc) {
        bf16x8 bb = ldsFrag(WT, w * 64 + fc * 16 + l15, ks * 64 + lg * 16, 256);
        acc[0][fc] = MFMA(a[0], bb, acc[0][fc]);
        acc[1][fc] = MFMA(a[1], bb, acc[1][fc]);
      }
    }
    __syncthreads();   // in-place: all reads of this tile done before any write
    #pragma unroll
    for (int fr = 0; fr < 2; ++fr)
      #pragma unroll
      for (int fc = 0; fc < 4; ++fc) {
        int col = w * 64 + fc * 16 + l15;
        #pragma unroll
        for (int i = 0; i < 4; ++i) {
          int r = fr * 16 + lg * 4 + i;
          float o = fmaxf(acc[fr][fc][i] + b1v[fc], 0.f);
          outH[(size_t)(rowBase + r) * 256 + col] = f2bf(o);
        }
      }
  }
}

// ------- readout stage 2 (MFMA, direct-global A): out = relu(h1 @ W2 + b2) . W3 + b3 ---------
__global__ __launch_bounds__(256) void k_ro2(
    const unsigned short* __restrict__ inH,   // rows x 256 bf16
    float* __restrict__ out, int nTiles,
    const float* __restrict__ W2, const float* __restrict__ b2,
    const float* __restrict__ W3, const float* __restrict__ b3)
{
  __shared__ char WT[128 * 512];   // 64 KB
  __shared__ float red[2][32][4];
  const int t = threadIdx.x;
  stageWT(W2, WT, 256, 128, 5);
  const int w   = t >> 6;
  const int l   = t & 63;
  const int l15 = l & 15;
  const int lg  = l >> 4;
  float b2v[2], w3v[2];
  #pragma unroll
  for (int fc = 0; fc < 2; ++fc) {
    int col = w * 32 + fc * 16 + l15;
    b2v[fc] = b2[col];
    w3v[fc] = W3[col];
  }
  const float b3v = b3[0];
  __syncthreads();

  int par = 0;
  for (int tile = blockIdx.x; tile < nTiles; tile += gridDim.x) {
    const int rowBase = tile << 5;
    f32x4 acc[2][2];
    #pragma unroll
    for (int fr = 0; fr < 2; ++fr)
      #pragma unroll
      for (int fc = 0; fc < 2; ++fc) acc[fr][fc] = (f32x4){0.f, 0.f, 0.f, 0.f};
    #pragma unroll
    for (int ks = 0; ks < 8; ++ks) {
      const int kb = ks * 64 + lg * 16;    // byte offset in 512 B row
      bf16x8 a0 = *(const bf16x8*)((const char*)inH + (size_t)(rowBase + l15) * 512 + kb);
      bf16x8 a1 = *(const bf16x8*)((const char*)inH + (size_t)(rowBase + 16 + l15) * 512 + kb);
      bf16x8 b0 = ldsFrag(WT, w * 32 + l15,      kb, 512);
      bf16x8 b1 = ldsFrag(WT, w * 32 + 16 + l15, kb, 512);
      acc[0][0] = MFMA(a0, b0, acc[0][0]);
      acc[0][1] = MFMA(a0, b1, acc[0][1]);
      acc[1][0] = MFMA(a1, b0, acc[1][0]);
      acc[1][1] = MFMA(a1, b1, acc[1][1]);
    }
    #pragma unroll
    for (int fr = 0; fr < 2; ++fr)
      #pragma unroll
      for (int i = 0; i < 4; ++i) {
        float p = fmaxf(acc[fr][0][i] + b2v[0], 0.f) * w3v[0]
                + fmaxf(acc[fr][1][i] + b2v[1], 0.f) * w3v[1];
        p += __shfl_xor(p, 1);
        p += __shfl_xor(p, 2);
        p += __shfl_xor(p, 4);
        p += __shfl_xor(p, 8);
        if (l15 == 0) red[par][fr * 16 + lg * 4 + i][w] = p;
      }
    __syncthreads();
    if (t < 32)
      out[rowBase + t] = red[par][t][0] + red[par][t][1] + red[par][t][2] + red[par][t][3] + b3v;
    par ^= 1;
  }
}

extern "C" void kernel_launch(void* const* d_in, const int* in_sizes, int n_in,
                              void* d_out, int out_size, void* d_ws, size_t ws_size,
                              hipStream_t stream)
{
  const float* x1     = (const float*)d_in[0];
  const float* x2     = (const float*)d_in[1];
  const float* Ac     = (const float*)d_in[2];
  const int*   edge   = (const int*)d_in[3];
  const float* node_W = (const float*)d_in[4];
  const float* node_b = (const float*)d_in[5];
  const float* mlp_W  = (const float*)d_in[6];
  const float* mlp_b  = (const float*)d_in[7];
  const float* egL_W  = (const float*)d_in[8];
  const float* egL_b  = (const float*)d_in[9];
  const float* nro_W1 = (const float*)d_in[10];
  const float* nro_b1 = (const float*)d_in[11];
  const float* nro_W2 = (const float*)d_in[12];
  const float* nro_b2 = (const float*)d_in[13];
  const float* nro_W3 = (const float*)d_in[14];
  const float* nro_b3 = (const float*)d_in[15];
  const float* ero_W1 = (const float*)d_in[16];
  const float* ero_b1 = (const float*)d_in[17];
  const float* ero_W2 = (const float*)d_in[18];
  const float* ero_b2 = (const float*)d_in[19];
  const float* ero_W3 = (const float*)d_in[20];
  const float* ero_b3 = (const float*)d_in[21];
  float* out = (float*)d_out;

  const size_t xnElems = (size_t)NB * NT * 2 * ND;       // 8,388,608
  const size_t xeElems = (size_t)NB * NM * 4 * ND;       // 134,217,728
  if (ws_size < (xnElems * 2 + xeElems) * sizeof(float)) return;

  float* xnA = (float*)d_ws;
  float* xnB = xnA + xnElems;
  float* xe  = xnB + xnElems;

  // CSR scratch lives in d_out (readouts overwrite it at the end)
  int* deg    = (int*)d_out;
  int* off    = deg + NT;
  int* cursor = off + NT + 1;
  int* csr    = cursor + NT;

  hipMemsetAsync(deg, 0, NT * sizeof(int), stream);
  k_csr_count<<<NM / 256, 256, 0, stream>>>(edge, deg);
  k_csr_scan<<<1, 64, 0, stream>>>(deg, off, cursor);
  k_csr_fill<<<NM / 256, 256, 0, stream>>>(edge, cursor, csr);
  k_csr_sort<<<NT / 256, 256, 0, stream>>>(off, csr);

  // layer 0 (reads x1/x2 directly; no memcpy)
  k_node<<<2048, 256, 0, stream>>>(x1, xnA, Ac, edge, off, csr, node_W, node_b, 0);
  k_edge_mfma<<<2048, 256, 0, stream>>>(xnA, x2, xe, edge, mlp_W, mlp_b, egL_W, egL_b, 1);
  // layer 1
  k_node<<<2048, 256, 0, stream>>>(xnA, xnB, Ac, edge, off, csr,
                                   node_W + ND * ND, node_b + ND, 1);
  k_edge_mfma<<<2048, 256, 0, stream>>>(xnB, xe, xe, edge,
                                        mlp_W + ND * ND, mlp_b + ND,
                                        egL_W + ND * ND, egL_b + ND, 1);
  // layer 2
  k_node<<<2048, 256, 0, stream>>>(xnB, xnA, Ac, edge, off, csr,
                                   node_W + 2 * ND * ND, node_b + 2 * ND, 1);
  k_edge_mfma<<<2048, 256, 0, stream>>>(xnA, xe, xe, edge,
                                        mlp_W + 2 * ND * ND, mlp_b + 2 * ND,
                                        egL_W + 2 * ND * ND, egL_b + 2 * ND, 0);
  // node readout (in-place over xnA)
  k_ro1<<<2048, 256, 0, stream>>>(xnA, (unsigned short*)xnA, (NB * NT * 2) / 32,
                                  nro_W1, nro_b1);
  k_ro2<<<2048, 256, 0, stream>>>((const unsigned short*)xnA, out, (NB * NT * 2) / 32,
                                  nro_W2, nro_b2, nro_W3, nro_b3);
  // edge readout (in-place over xe)
  k_ro1<<<2048, 256, 0, stream>>>(xe, (unsigned short*)xe, (NB * NM * 4) / 32,
                                  ero_W1, ero_b1);
  k_ro2<<<2048, 256, 0, stream>>>((const unsigned short*)xe, out + NB * NT * 2,
                                  (NB * NM * 4) / 32,
                                  ero_W2, ero_b2, ero_W3, ero_b3);
}

// Round 5
// 2285.339 us; speedup vs baseline: 4.5091x; 1.1333x over previous
//
#include <hip/hip_runtime.h>

#define NB 8
#define NT 4096
#define NM 32768
#define ND 128

typedef __attribute__((ext_vector_type(8))) short bf16x8;
typedef __attribute__((ext_vector_type(4))) float f32x4;
typedef __attribute__((ext_vector_type(4))) unsigned int u32x4;

#define MFMA(a,b,c) __builtin_amdgcn_mfma_f32_16x16x32_bf16(a,b,c,0,0,0)

// ---- bf16 helpers (RNE) ----
__device__ __forceinline__ unsigned short f2bf(float x) {
  unsigned u = __float_as_uint(x);
  u += 0x7FFFu + ((u >> 16) & 1u);
  return (unsigned short)(u >> 16);
}

// XOR-swizzled LDS fragment read: 8 consecutive bf16 at (row, kByte)
__device__ __forceinline__ bf16x8 ldsFrag(const char* lds, int row, int kByte, int rowStride) {
  return *(const bf16x8*)(lds + ((row * rowStride + kByte) ^ ((row & 7) << 4)));
}

// Stage W[K][N] (f32, row-major) -> LDS WT[N][K] bf16, XOR-swizzled rows.
__device__ __forceinline__ void stageWT(const float* __restrict__ W, char* lds,
                                        int K, int N, int khShift, int nthr) {
  const int khn = 1 << khShift;
  const int rowStride = K * 2;
  for (int i = threadIdx.x; i < (N << khShift); i += nthr) {
    int n = i >> khShift, kh = i & (khn - 1);
    int k0 = kh << 3;
    unsigned short tmp[8];
    #pragma unroll
    for (int j = 0; j < 8; ++j) tmp[j] = f2bf(W[(k0 + j) * N + n]);
    *(u32x4*)(lds + ((n * rowStride + k0 * 2) ^ ((n & 7) << 4))) = *(u32x4*)tmp;
  }
}

// ================= CSR build (edges constant across layers; deterministic) =================
__global__ __launch_bounds__(256) void k_csr_count(const int* __restrict__ edge, int* deg) {
  int m = blockIdx.x * 256 + threadIdx.x;
  if (m < NM) atomicAdd(&deg[edge[m]], 1);
}
__global__ __launch_bounds__(64) void k_csr_scan(const int* __restrict__ deg,
                                                 int* __restrict__ off, int* __restrict__ cursor) {
  __shared__ int partial[64];
  int t = threadIdx.x;
  int base = t * 64;
  int sum = 0;
  for (int i = 0; i < 64; ++i) sum += deg[base + i];
  partial[t] = sum;
  __syncthreads();
  if (t == 0) {
    int run = 0;
    for (int i = 0; i < 64; ++i) { int v = partial[i]; partial[i] = run; run += v; }
  }
  __syncthreads();
  int run = partial[t];
  for (int i = 0; i < 64; ++i) {
    off[base + i] = run; cursor[base + i] = run;
    run += deg[base + i];
  }
  if (t == 63) off[NT] = NM;
}
__global__ __launch_bounds__(256) void k_csr_fill(const int* __restrict__ edge,
                                                  int* cursor, int* __restrict__ csr) {
  int m = blockIdx.x * 256 + threadIdx.x;
  if (m < NM) { int pos = atomicAdd(&cursor[edge[m]], 1); csr[pos] = m; }
}
__global__ __launch_bounds__(256) void k_csr_sort(const int* __restrict__ off, int* __restrict__ csr) {
  int n = blockIdx.x * 256 + threadIdx.x;
  if (n < NT) {
    int s = off[n], e = off[n + 1];
    for (int i = s + 1; i < e; ++i) {
      int v = csr[i]; int j = i - 1;
      while (j >= s && csr[j] > v) { csr[j + 1] = csr[j]; --j; }
      csr[j + 1] = v;
    }
  }
}

// ====== fused node layer: xnOut = (relu?(xnIn) + gatherCSR(xnIn)) @ W + b  (f32 GEMM) ======
__global__ __launch_bounds__(256) void k_node(
    const float* __restrict__ xnIn, float* __restrict__ xnOut,
    const float* __restrict__ A, const int* __restrict__ edge,
    const int* __restrict__ off, const int* __restrict__ csr,
    const float* __restrict__ W, const float* __restrict__ bias, int doReluIn)
{
  __shared__ float Ws[ND * ND];     // 64 KB
  __shared__ float xs[32][ND];      // 16 KB  -> 80 KB, 2 blocks/CU
  const int t = threadIdx.x;
  for (int i = t; i < ND * ND; i += 256) Ws[i] = W[i];

  const int rowBase = blockIdx.x << 5;
  // ---- gather phase: 8 threads per row, 16 f32 accumulators each ----
  {
    const int r  = t >> 3;
    const int c0 = (t & 7) << 4;
    const int grow = rowBase + r;
    const int ch   = grow & 1;
    const int node = (grow >> 1) & (NT - 1);
    const int b    = grow >> 13;
    f32x4 acc[4];
    {
      const float4* xr = (const float4*)(xnIn + (size_t)grow * ND + c0);
      #pragma unroll
      for (int q = 0; q < 4; ++q) {
        float4 v = xr[q];
        if (doReluIn) {
          v.x = fmaxf(v.x, 0.f); v.y = fmaxf(v.y, 0.f);
          v.z = fmaxf(v.z, 0.f); v.w = fmaxf(v.w, 0.f);
        }
        acc[q] = (f32x4){v.x, v.y, v.z, v.w};
      }
    }
    const int s = off[node], e = off[node + 1];
    for (int p = s; p < e; ++p) {
      int m = csr[p];
      float a = A[b * NM + m];
      int e1 = edge[NM + m];
      const float4* src = (const float4*)(xnIn + (size_t)(((b * NT + e1) << 1) + ch) * ND + c0);
      #pragma unroll
      for (int q = 0; q < 4; ++q) {
        float4 v = src[q];
        if (doReluIn) {
          v.x = fmaxf(v.x, 0.f); v.y = fmaxf(v.y, 0.f);
          v.z = fmaxf(v.z, 0.f); v.w = fmaxf(v.w, 0.f);
        }
        acc[q][0] = fmaf(a, v.x, acc[q][0]);
        acc[q][1] = fmaf(a, v.y, acc[q][1]);
        acc[q][2] = fmaf(a, v.z, acc[q][2]);
        acc[q][3] = fmaf(a, v.w, acc[q][3]);
      }
    }
    #pragma unroll
    for (int q = 0; q < 4; ++q) *(f32x4*)&xs[r][c0 + q * 4] = acc[q];
  }
  const int c4 = (t & 31) << 2;
  const int rg = t >> 5;
  float4 bv = *(const float4*)(bias + c4);
  __syncthreads();
  float acc[4][4];
  #pragma unroll
  for (int r = 0; r < 4; ++r)
    #pragma unroll
    for (int c = 0; c < 4; ++c) acc[r][c] = 0.f;
  for (int k = 0; k < ND; k += 4) {
    float4 sv[4];
    #pragma unroll
    for (int r = 0; r < 4; ++r) sv[r] = *(const float4*)&xs[(rg << 2) + r][k];
    #pragma unroll
    for (int j = 0; j < 4; ++j) {
      float4 w = *(const float4*)&Ws[(k + j) * ND + c4];
      #pragma unroll
      for (int r = 0; r < 4; ++r) {
        float s = ((const float*)&sv[r])[j];
        acc[r][0] += s * w.x; acc[r][1] += s * w.y;
        acc[r][2] += s * w.z; acc[r][3] += s * w.w;
      }
    }
  }
  #pragma unroll
  for (int r = 0; r < 4; ++r) {
    float4 o;
    o.x = acc[r][0] + bv.x; o.y = acc[r][1] + bv.y;
    o.z = acc[r][2] + bv.z; o.w = acc[r][3] + bv.w;
    *(float4*)&xnOut[(size_t)(rowBase + (rg << 2) + r) * ND + c4] = o;
  }
}

// ------- edge layer (MFMA, 64-row tiles): xeOut = relu?((xeIn + (ei+ej)@Wm + bm)@We + be) ----
__global__ __launch_bounds__(256) void k_edge_mfma(
    const float* __restrict__ xn, const float* __restrict__ xeIn, float* xeOut,
    const int* __restrict__ edge,
    const float* __restrict__ Wm, const float* __restrict__ bm,
    const float* __restrict__ We, const float* __restrict__ be,
    int doReluOut)
{
  __shared__ char WmT[128 * 256];   // 32 KB
  __shared__ char WeT[128 * 256];   // 32 KB
  __shared__ char sA[64 * 256];     // 16 KB -> 80 KB, 2 blocks/CU
  const int t = threadIdx.x;
  stageWT(Wm, WmT, 128, 128, 4, 256);
  stageWT(We, WeT, 128, 128, 4, 256);
  const int w   = t >> 6;
  const int l   = t & 63;
  const int l15 = l & 15;
  const int lg  = l >> 4;
  float bmv[2], bev[2];
  #pragma unroll
  for (int fc = 0; fc < 2; ++fc) {
    int col = w * 32 + fc * 16 + l15;
    bmv[fc] = bm[col];
    bev[fc] = be[col];
  }
  const int srow = t >> 2;          // 64 rows, 4 threads/row
  __syncthreads();

  const int nTiles = (NB * NM * 4) / 64;   // 16384
  for (int tile = blockIdx.x; tile < nTiles; tile += gridDim.x) {
    const int rowBase = tile << 6;
    // ---- stage sA = bf16(xn[e0,ni] + xn[e1,nj])  (64 rows x 128) ----
    {
      int grow = rowBase + srow;
      int cch = grow & 3;
      int m = (grow >> 2) & (NM - 1);
      int b = grow >> 17;
      int e0 = edge[m], e1 = edge[NM + m];
      const float4* p0 = (const float4*)(xn + (size_t)((b * NT + e0) * 2 + (cch >> 1)) * ND);
      const float4* p1 = (const float4*)(xn + (size_t)((b * NT + e1) * 2 + (cch & 1)) * ND);
      #pragma unroll
      for (int hh = 0; hh < 4; ++hh) {
        int h = (t & 3) + hh * 4;          // 16B slot 0..15
        float4 a0 = p0[h * 2], a1 = p0[h * 2 + 1];
        float4 c0 = p1[h * 2], c1 = p1[h * 2 + 1];
        unsigned short tmp[8];
        tmp[0] = f2bf(a0.x + c0.x); tmp[1] = f2bf(a0.y + c0.y);
        tmp[2] = f2bf(a0.z + c0.z); tmp[3] = f2bf(a0.w + c0.w);
        tmp[4] = f2bf(a1.x + c1.x); tmp[5] = f2bf(a1.y + c1.y);
        tmp[6] = f2bf(a1.z + c1.z); tmp[7] = f2bf(a1.w + c1.w);
        *(u32x4*)(sA + ((srow * 256 + h * 16) ^ ((srow & 7) << 4))) = *(u32x4*)tmp;
      }
    }
    // ---- prefetch xe tile into registers (T14: issue early, consume after phase A) ----
    float xev[4][2][4];
    #pragma unroll
    for (int fr = 0; fr < 4; ++fr)
      #pragma unroll
      for (int fc = 0; fc < 2; ++fc) {
        int col = w * 32 + fc * 16 + l15;
        #pragma unroll
        for (int i = 0; i < 4; ++i) {
          int r = fr * 16 + lg * 4 + i;
          xev[fr][fc][i] = xeIn[(size_t)(rowBase + r) * ND + col];
        }
      }
    __syncthreads();
    // ---- phase A: T = sA @ Wm ----
    f32x4 acc[4][2];
    #pragma unroll
    for (int fr = 0; fr < 4; ++fr)
      #pragma unroll
      for (int fc = 0; fc < 2; ++fc) acc[fr][fc] = (f32x4){0.f, 0.f, 0.f, 0.f};
    #pragma unroll
    for (int ks = 0; ks < 4; ++ks) {
      int kb = ks * 64 + lg * 16;
      bf16x8 b0 = ldsFrag(WmT, w * 32 + l15,      kb, 256);
      bf16x8 b1 = ldsFrag(WmT, w * 32 + 16 + l15, kb, 256);
      #pragma unroll
      for (int fr = 0; fr < 4; ++fr) {
        bf16x8 a = ldsFrag(sA, fr * 16 + l15, kb, 256);
        acc[fr][0] = MFMA(a, b0, acc[fr][0]);
        acc[fr][1] = MFMA(a, b1, acc[fr][1]);
      }
    }
    __syncthreads();
    // ---- v = xev + T + bm -> sA (bf16) ----
    #pragma unroll
    for (int fr = 0; fr < 4; ++fr)
      #pragma unroll
      for (int fc = 0; fc < 2; ++fc) {
        int col = w * 32 + fc * 16 + l15;
        #pragma unroll
        for (int i = 0; i < 4; ++i) {
          int r = fr * 16 + lg * 4 + i;
          float v = xev[fr][fc][i] + acc[fr][fc][i] + bmv[fc];
          *(unsigned short*)(sA + ((r * 256 + col * 2) ^ ((r & 7) << 4))) = f2bf(v);
        }
      }
    __syncthreads();
    // ---- phase B: O = v @ We ----
    #pragma unroll
    for (int fr = 0; fr < 4; ++fr)
      #pragma unroll
      for (int fc = 0; fc < 2; ++fc) acc[fr][fc] = (f32x4){0.f, 0.f, 0.f, 0.f};
    #pragma unroll
    for (int ks = 0; ks < 4; ++ks) {
      int kb = ks * 64 + lg * 16;
      bf16x8 b0 = ldsFrag(WeT, w * 32 + l15,      kb, 256);
      bf16x8 b1 = ldsFrag(WeT, w * 32 + 16 + l15, kb, 256);
      #pragma unroll
      for (int fr = 0; fr < 4; ++fr) {
        bf16x8 a = ldsFrag(sA, fr * 16 + l15, kb, 256);
        acc[fr][0] = MFMA(a, b0, acc[fr][0]);
        acc[fr][1] = MFMA(a, b1, acc[fr][1]);
      }
    }
    __syncthreads();   // sA free for next tile
    // ---- epilogue ----
    #pragma unroll
    for (int fr = 0; fr < 4; ++fr)
      #pragma unroll
      for (int fc = 0; fc < 2; ++fc) {
        int col = w * 32 + fc * 16 + l15;
        #pragma unroll
        for (int i = 0; i < 4; ++i) {
          int r = fr * 16 + lg * 4 + i;
          float o = acc[fr][fc][i] + bev[fc];
          if (doReluOut) o = fmaxf(o, 0.f);
          xeOut[(size_t)(rowBase + r) * ND + col] = o;
        }
      }
  }
}

// ====== fused readout: out = relu(relu(x@W1+b1)@W2+b2).W3 + b3  (512 thr, all-LDS) ======
__global__ __launch_bounds__(512) void k_ro_fused(
    const float* __restrict__ inF, float* __restrict__ out, int nTiles,
    const float* __restrict__ W1, const float* __restrict__ b1,
    const float* __restrict__ W2, const float* __restrict__ b2,
    const float* __restrict__ W3, const float* __restrict__ b3)
{
  __shared__ char W1T[256 * 256];   // [256 n][128 k] bf16 swz, 64 KB
  __shared__ char W2T[128 * 512];   // [128 n][256 k] bf16 swz, 64 KB
  __shared__ char sA[32 * 256];     // 32 rows x 128 bf16, 8 KB
  __shared__ char h1[32 * 512];     // 32 rows x 256 bf16, 16 KB
  __shared__ float red[2][32][8];   // 2 KB  -> total 154 KB, 1 block/CU
  const int t = threadIdx.x;
  stageWT(W1, W1T, 128, 256, 4, 512);
  stageWT(W2, W2T, 256, 128, 5, 512);
  const int w   = t >> 6;           // wave 0..7
  const int l   = t & 63;
  const int l15 = l & 15;
  const int lg  = l >> 4;
  // phase-1: wave w -> cols w*32 .. w*32+31 of 256
  float b1v[2];
  #pragma unroll
  for (int fc = 0; fc < 2; ++fc) b1v[fc] = b1[w * 32 + fc * 16 + l15];
  // phase-2: wave w -> cols w*16 .. w*16+15 of 128
  const float b2v = b2[w * 16 + l15];
  const float w3v = W3[w * 16 + l15];
  const float b3v = b3[0];
  const int srow = t >> 4;          // staging: 32 rows, 16 threads/row
  __syncthreads();

  int par = 0;
  for (int tile = blockIdx.x; tile < nTiles; tile += gridDim.x) {
    const int rowBase = tile << 5;
    // ---- stage x tile -> sA bf16 (coalesced) ----
    {
      const float4* p = (const float4*)(inF + (size_t)(rowBase + srow) * ND + (t & 15) * 8);
      float4 v0 = p[0], v1 = p[1];
      unsigned short tmp[8];
      tmp[0] = f2bf(v0.x); tmp[1] = f2bf(v0.y); tmp[2] = f2bf(v0.z); tmp[3] = f2bf(v0.w);
      tmp[4] = f2bf(v1.x); tmp[5] = f2bf(v1.y); tmp[6] = f2bf(v1.z); tmp[7] = f2bf(v1.w);
      *(u32x4*)(sA + ((srow * 256 + (t & 15) * 16) ^ ((srow & 7) << 4))) = *(u32x4*)tmp;
    }
    __syncthreads();
    // ---- phase 1: h1 = relu(x @ W1 + b1)   (32 x 256) ----
    {
      f32x4 acc[2][2];
      #pragma unroll
      for (int fr = 0; fr < 2; ++fr)
        #pragma unroll
        for (int fc = 0; fc < 2; ++fc) acc[fr][fc] = (f32x4){0.f, 0.f, 0.f, 0.f};
      #pragma unroll
      for (int ks = 0; ks < 4; ++ks) {
        int kb = ks * 64 + lg * 16;
        bf16x8 a0 = ldsFrag(sA, l15,      kb, 256);
        bf16x8 a1 = ldsFrag(sA, 16 + l15, kb, 256);
        bf16x8 b0 = ldsFrag(W1T, w * 32 + l15,      kb, 256);
        bf16x8 b1f = ldsFrag(W1T, w * 32 + 16 + l15, kb, 256);
        acc[0][0] = MFMA(a0, b0, acc[0][0]);
        acc[0][1] = MFMA(a0, b1f, acc[0][1]);
        acc[1][0] = MFMA(a1, b0, acc[1][0]);
        acc[1][1] = MFMA(a1, b1f, acc[1][1]);
      }
      __syncthreads();   // all phase-1 sA reads done (also gates h1 writes vs phase-2 reads below)
      #pragma unroll
      for (int fr = 0; fr < 2; ++fr)
        #pragma unroll
        for (int fc = 0; fc < 2; ++fc) {
          int col = w * 32 + fc * 16 + l15;
          #pragma unroll
          for (int i = 0; i < 4; ++i) {
            int r = fr * 16 + lg * 4 + i;
            float o = fmaxf(acc[fr][fc][i] + b1v[fc], 0.f);
            *(unsigned short*)(h1 + ((r * 512 + col * 2) ^ ((r & 7) << 4))) = f2bf(o);
          }
        }
    }
    __syncthreads();
    // ---- phase 2: h2 = relu(h1 @ W2 + b2); p = h2 . W3 ----
    {
      f32x4 acc[2];
      acc[0] = (f32x4){0.f, 0.f, 0.f, 0.f};
      acc[1] = (f32x4){0.f, 0.f, 0.f, 0.f};
      #pragma unroll
      for (int ks = 0; ks < 8; ++ks) {
        int kb = ks * 64 + lg * 16;
        bf16x8 a0 = ldsFrag(h1, l15,      kb, 512);
        bf16x8 a1 = ldsFrag(h1, 16 + l15, kb, 512);
        bf16x8 bb = ldsFrag(W2T, w * 16 + l15, kb, 512);
        acc[0] = MFMA(a0, bb, acc[0]);
        acc[1] = MFMA(a1, bb, acc[1]);
      }
      #pragma unroll
      for (int fr = 0; fr < 2; ++fr)
        #pragma unroll
        for (int i = 0; i < 4; ++i) {
          float p = fmaxf(acc[fr][i] + b2v, 0.f) * w3v;
          p += __shfl_xor(p, 1);
          p += __shfl_xor(p, 2);
          p += __shfl_xor(p, 4);
          p += __shfl_xor(p, 8);
          if (l15 == 0) red[par][fr * 16 + lg * 4 + i][w] = p;
        }
    }
    __syncthreads();   // red ready; h1/sA reads done -> next tile may restage
    if (t < 32) {
      float s = b3v;
      #pragma unroll
      for (int q = 0; q < 8; ++q) s += red[par][t][q];
      out[rowBase + t] = s;
    }
    par ^= 1;
  }
}

extern "C" void kernel_launch(void* const* d_in, const int* in_sizes, int n_in,
                              void* d_out, int out_size, void* d_ws, size_t ws_size,
                              hipStream_t stream)
{
  const float* x1     = (const float*)d_in[0];
  const float* x2     = (const float*)d_in[1];
  const float* Ac     = (const float*)d_in[2];
  const int*   edge   = (const int*)d_in[3];
  const float* node_W = (const float*)d_in[4];
  const float* node_b = (const float*)d_in[5];
  const float* mlp_W  = (const float*)d_in[6];
  const float* mlp_b  = (const float*)d_in[7];
  const float* egL_W  = (const float*)d_in[8];
  const float* egL_b  = (const float*)d_in[9];
  const float* nro_W1 = (const float*)d_in[10];
  const float* nro_b1 = (const float*)d_in[11];
  const float* nro_W2 = (const float*)d_in[12];
  const float* nro_b2 = (const float*)d_in[13];
  const float* nro_W3 = (const float*)d_in[14];
  const float* nro_b3 = (const float*)d_in[15];
  const float* ero_W1 = (const float*)d_in[16];
  const float* ero_b1 = (const float*)d_in[17];
  const float* ero_W2 = (const float*)d_in[18];
  const float* ero_b2 = (const float*)d_in[19];
  const float* ero_W3 = (const float*)d_in[20];
  const float* ero_b3 = (const float*)d_in[21];
  float* out = (float*)d_out;

  const size_t xnElems = (size_t)NB * NT * 2 * ND;       // 8,388,608
  const size_t xeElems = (size_t)NB * NM * 4 * ND;       // 134,217,728
  if (ws_size < (xnElems * 2 + xeElems) * sizeof(float)) return;

  float* xnA = (float*)d_ws;
  float* xnB = xnA + xnElems;
  float* xe  = xnB + xnElems;

  // CSR scratch lives in d_out (readouts overwrite it at the end)
  int* deg    = (int*)d_out;
  int* off    = deg + NT;
  int* cursor = off + NT + 1;
  int* csr    = cursor + NT;

  hipMemsetAsync(deg, 0, NT * sizeof(int), stream);
  k_csr_count<<<NM / 256, 256, 0, stream>>>(edge, deg);
  k_csr_scan<<<1, 64, 0, stream>>>(deg, off, cursor);
  k_csr_fill<<<NM / 256, 256, 0, stream>>>(edge, cursor, csr);
  k_csr_sort<<<NT / 256, 256, 0, stream>>>(off, csr);

  // layer 0 (reads x1/x2 directly; no memcpy)
  k_node<<<2048, 256, 0, stream>>>(x1, xnA, Ac, edge, off, csr, node_W, node_b, 0);
  k_edge_mfma<<<2048, 256, 0, stream>>>(xnA, x2, xe, edge, mlp_W, mlp_b, egL_W, egL_b, 1);
  // layer 1
  k_node<<<2048, 256, 0, stream>>>(xnA, xnB, Ac, edge, off, csr,
                                   node_W + ND * ND, node_b + ND, 1);
  k_edge_mfma<<<2048, 256, 0, stream>>>(xnB, xe, xe, edge,
                                        mlp_W + ND * ND, mlp_b + ND,
                                        egL_W + ND * ND, egL_b + ND, 1);
  // layer 2
  k_node<<<2048, 256, 0, stream>>>(xnB, xnA, Ac, edge, off, csr,
                                   node_W + 2 * ND * ND, node_b + 2 * ND, 1);
  k_edge_mfma<<<2048, 256, 0, stream>>>(xnA, xe, xe, edge,
                                        mlp_W + 2 * ND * ND, mlp_b + 2 * ND,
                                        egL_W + 2 * ND * ND, egL_b + 2 * ND, 0);
  // fused readouts (no h1 round trip)
  k_ro_fused<<<2048, 512, 0, stream>>>(xnA, out, (NB * NT * 2) / 32,
                                       nro_W1, nro_b1, nro_W2, nro_b2, nro_W3, nro_b3);
  k_ro_fused<<<2048, 512, 0, stream>>>(xe, out + NB * NT * 2, (NB * NM * 4) / 32,
                                       ero_W1, ero_b1, ero_W2, ero_b2, ero_W3, ero_b3);
}

// Round 6
// 1543.411 us; speedup vs baseline: 6.6766x; 1.4807x over previous
//
#include <hip/hip_runtime.h>

#define NB 8
#define NT 4096
#define NM 32768
#define ND 128

typedef __attribute__((ext_vector_type(8))) short bf16x8;
typedef __attribute__((ext_vector_type(4))) float f32x4;
typedef __attribute__((ext_vector_type(4))) unsigned int u32x4;

#define MFMA(a,b,c) __builtin_amdgcn_mfma_f32_16x16x32_bf16(a,b,c,0,0,0)

// ---- bf16 helpers (RNE) ----
__device__ __forceinline__ unsigned short f2bf(float x) {
  unsigned u = __float_as_uint(x);
  u += 0x7FFFu + ((u >> 16) & 1u);
  return (unsigned short)(u >> 16);
}

// XOR-swizzled LDS fragment read: 8 consecutive bf16 at (row, kByte)
__device__ __forceinline__ bf16x8 ldsFrag(const char* lds, int row, int kByte, int rowStride) {
  return *(const bf16x8*)(lds + ((row * rowStride + kByte) ^ ((row & 7) << 4)));
}

// ============ weight prep: W[K][N] f32 -> pre-swizzled bf16 image [N][K] (T-layout) ============
__global__ __launch_bounds__(256) void k_prep(
    const float* __restrict__ W, char* __restrict__ dst,
    int K, int N, int khShift, int perShift, int total)
{
  int i = blockIdx.x * 256 + threadIdx.x;
  if (i >= total) return;
  int m  = i >> perShift;
  int j  = i & ((1 << perShift) - 1);
  int n  = j >> khShift;
  int kh = j & ((1 << khShift) - 1);
  int k0 = kh << 3;
  const float* Wm = W + (size_t)m * K * N;
  char* dm = dst + (size_t)m * K * N * 2;
  unsigned short tmp[8];
  #pragma unroll
  for (int jj = 0; jj < 8; ++jj) tmp[jj] = f2bf(Wm[(k0 + jj) * N + n]);
  *(u32x4*)(dm + ((n * K * 2 + k0 * 2) ^ ((n & 7) << 4))) = *(u32x4*)tmp;
}

// ================= CSR build (edges constant across layers; deterministic) =================
__global__ __launch_bounds__(256) void k_csr_count(const int* __restrict__ edge, int* deg) {
  int m = blockIdx.x * 256 + threadIdx.x;
  if (m < NM) atomicAdd(&deg[edge[m]], 1);
}
__global__ __launch_bounds__(64) void k_csr_scan(const int* __restrict__ deg,
                                                 int* __restrict__ off, int* __restrict__ cursor) {
  __shared__ int partial[64];
  int t = threadIdx.x;
  int base = t * 64;
  int sum = 0;
  for (int i = 0; i < 64; ++i) sum += deg[base + i];
  partial[t] = sum;
  __syncthreads();
  if (t == 0) {
    int run = 0;
    for (int i = 0; i < 64; ++i) { int v = partial[i]; partial[i] = run; run += v; }
  }
  __syncthreads();
  int run = partial[t];
  for (int i = 0; i < 64; ++i) {
    off[base + i] = run; cursor[base + i] = run;
    run += deg[base + i];
  }
  if (t == 63) off[NT] = NM;
}
__global__ __launch_bounds__(256) void k_csr_fill(const int* __restrict__ edge,
                                                  int* cursor, int* __restrict__ csr) {
  int m = blockIdx.x * 256 + threadIdx.x;
  if (m < NM) { int pos = atomicAdd(&cursor[edge[m]], 1); csr[pos] = m; }
}
__global__ __launch_bounds__(256) void k_csr_sort(const int* __restrict__ off, int* __restrict__ csr) {
  int n = blockIdx.x * 256 + threadIdx.x;
  if (n < NT) {
    int s = off[n], e = off[n + 1];
    for (int i = s + 1; i < e; ++i) {
      int v = csr[i]; int j = i - 1;
      while (j >= s && csr[j] > v) { csr[j + 1] = csr[j]; --j; }
      csr[j + 1] = v;
    }
  }
}

// ====== fused node layer: xnOut = (relu?(xnIn) + gatherCSR(xnIn)) @ W + b  (f32 GEMM) ======
__global__ __launch_bounds__(256) void k_node(
    const float* __restrict__ xnIn, float* __restrict__ xnOut,
    const float* __restrict__ A, const int* __restrict__ edge,
    const int* __restrict__ off, const int* __restrict__ csr,
    const float* __restrict__ W, const float* __restrict__ bias, int doReluIn)
{
  __shared__ float Ws[ND * ND];     // 64 KB
  __shared__ float xs[32][ND];      // 16 KB  -> 80 KB, 2 blocks/CU
  const int t = threadIdx.x;
  for (int i = t; i < ND * ND; i += 256) Ws[i] = W[i];

  const int rowBase = blockIdx.x << 5;
  {
    const int r  = t >> 3;
    const int c0 = (t & 7) << 4;
    const int grow = rowBase + r;
    const int ch   = grow & 1;
    const int node = (grow >> 1) & (NT - 1);
    const int b    = grow >> 13;
    f32x4 acc[4];
    {
      const float4* xr = (const float4*)(xnIn + (size_t)grow * ND + c0);
      #pragma unroll
      for (int q = 0; q < 4; ++q) {
        float4 v = xr[q];
        if (doReluIn) {
          v.x = fmaxf(v.x, 0.f); v.y = fmaxf(v.y, 0.f);
          v.z = fmaxf(v.z, 0.f); v.w = fmaxf(v.w, 0.f);
        }
        acc[q] = (f32x4){v.x, v.y, v.z, v.w};
      }
    }
    const int s = off[node], e = off[node + 1];
    for (int p = s; p < e; ++p) {
      int m = csr[p];
      float a = A[b * NM + m];
      int e1 = edge[NM + m];
      const float4* src = (const float4*)(xnIn + (size_t)(((b * NT + e1) << 1) + ch) * ND + c0);
      #pragma unroll
      for (int q = 0; q < 4; ++q) {
        float4 v = src[q];
        if (doReluIn) {
          v.x = fmaxf(v.x, 0.f); v.y = fmaxf(v.y, 0.f);
          v.z = fmaxf(v.z, 0.f); v.w = fmaxf(v.w, 0.f);
        }
        acc[q][0] = fmaf(a, v.x, acc[q][0]);
        acc[q][1] = fmaf(a, v.y, acc[q][1]);
        acc[q][2] = fmaf(a, v.z, acc[q][2]);
        acc[q][3] = fmaf(a, v.w, acc[q][3]);
      }
    }
    #pragma unroll
    for (int q = 0; q < 4; ++q) *(f32x4*)&xs[r][c0 + q * 4] = acc[q];
  }
  const int c4 = (t & 31) << 2;
  const int rg = t >> 5;
  float4 bv = *(const float4*)(bias + c4);
  __syncthreads();
  float acc[4][4];
  #pragma unroll
  for (int r = 0; r < 4; ++r)
    #pragma unroll
    for (int c = 0; c < 4; ++c) acc[r][c] = 0.f;
  for (int k = 0; k < ND; k += 4) {
    float4 sv[4];
    #pragma unroll
    for (int r = 0; r < 4; ++r) sv[r] = *(const float4*)&xs[(rg << 2) + r][k];
    #pragma unroll
    for (int j = 0; j < 4; ++j) {
      float4 w = *(const float4*)&Ws[(k + j) * ND + c4];
      #pragma unroll
      for (int r = 0; r < 4; ++r) {
        float s = ((const float*)&sv[r])[j];
        acc[r][0] += s * w.x; acc[r][1] += s * w.y;
        acc[r][2] += s * w.z; acc[r][3] += s * w.w;
      }
    }
  }
  #pragma unroll
  for (int r = 0; r < 4; ++r) {
    float4 o;
    o.x = acc[r][0] + bv.x; o.y = acc[r][1] + bv.y;
    o.z = acc[r][2] + bv.z; o.w = acc[r][3] + bv.w;
    *(float4*)&xnOut[(size_t)(rowBase + (rg << 2) + r) * ND + c4] = o;
  }
}

// ------ edge layer (MFMA, 512 thr, 64-row tiles): xeOut = relu?((xeIn+(ei+ej)@Wm+bm)@We+be) --
__global__ __launch_bounds__(512, 4) void k_edge_mfma(
    const float* __restrict__ xn, const float* __restrict__ xeIn, float* xeOut,
    const int* __restrict__ edge,
    const char* __restrict__ WmImg, const float* __restrict__ bm,
    const char* __restrict__ WeImg, const float* __restrict__ be,
    int doReluOut, int nTiles)
{
  __shared__ __align__(16) char WmT[128 * 256];   // 32 KB
  __shared__ __align__(16) char WeT[128 * 256];   // 32 KB
  __shared__ __align__(16) char sA[64 * 256];     // 16 KB -> 80 KB, 2 blocks/CU
  const int t = threadIdx.x;
  {
    const u32x4* sm = (const u32x4*)WmImg;
    const u32x4* se = (const u32x4*)WeImg;
    u32x4* dm = (u32x4*)WmT;
    u32x4* de = (u32x4*)WeT;
    for (int i = t; i < 2048; i += 512) { dm[i] = sm[i]; de[i] = se[i]; }
  }
  const int w   = t >> 6;          // 0..7
  const int l   = t & 63;
  const int l15 = l & 15;
  const int lg  = l >> 4;
  const int rg2 = w >> 2;          // row half (32 rows)
  const int wc  = w & 3;           // col quarter (32 cols)
  float bmv[2], bev[2];
  #pragma unroll
  for (int fc = 0; fc < 2; ++fc) {
    int col = wc * 32 + fc * 16 + l15;
    bmv[fc] = bm[col];
    bev[fc] = be[col];
  }
  const int srow = t >> 3;         // 64 rows, 8 threads/row
  __syncthreads();

  for (int tile = blockIdx.x; tile < nTiles; tile += gridDim.x) {
    const int rowBase = tile << 6;
    // ---- stage sA = bf16(xn[e0,ni] + xn[e1,nj])  (64 rows x 128) ----
    {
      int grow = rowBase + srow;
      int cch = grow & 3;
      int m = (grow >> 2) & (NM - 1);
      int b = grow >> 17;
      int e0 = edge[m], e1 = edge[NM + m];
      const float4* p0 = (const float4*)(xn + (size_t)((b * NT + e0) * 2 + (cch >> 1)) * ND);
      const float4* p1 = (const float4*)(xn + (size_t)((b * NT + e1) * 2 + (cch & 1)) * ND);
      #pragma unroll
      for (int hh = 0; hh < 2; ++hh) {
        int h = (t & 7) + hh * 8;          // 16B slot 0..15
        float4 a0 = p0[h * 2], a1 = p0[h * 2 + 1];
        float4 c0 = p1[h * 2], c1 = p1[h * 2 + 1];
        unsigned short tmp[8];
        tmp[0] = f2bf(a0.x + c0.x); tmp[1] = f2bf(a0.y + c0.y);
        tmp[2] = f2bf(a0.z + c0.z); tmp[3] = f2bf(a0.w + c0.w);
        tmp[4] = f2bf(a1.x + c1.x); tmp[5] = f2bf(a1.y + c1.y);
        tmp[6] = f2bf(a1.z + c1.z); tmp[7] = f2bf(a1.w + c1.w);
        *(u32x4*)(sA + ((srow * 256 + h * 16) ^ ((srow & 7) << 4))) = *(u32x4*)tmp;
      }
    }
    // ---- prefetch xe tile into registers (consumed after phase A) ----
    float xev[2][2][4];
    #pragma unroll
    for (int fr = 0; fr < 2; ++fr)
      #pragma unroll
      for (int fc = 0; fc < 2; ++fc) {
        int col = wc * 32 + fc * 16 + l15;
        #pragma unroll
        for (int i = 0; i < 4; ++i) {
          int r = rg2 * 32 + fr * 16 + lg * 4 + i;
          xev[fr][fc][i] = xeIn[(size_t)(rowBase + r) * ND + col];
        }
      }
    __syncthreads();
    // ---- phase A: T = sA @ Wm ----
    f32x4 acc[2][2];
    #pragma unroll
    for (int fr = 0; fr < 2; ++fr)
      #pragma unroll
      for (int fc = 0; fc < 2; ++fc) acc[fr][fc] = (f32x4){0.f, 0.f, 0.f, 0.f};
    #pragma unroll
    for (int ks = 0; ks < 4; ++ks) {
      int kb = ks * 64 + lg * 16;
      bf16x8 b0 = ldsFrag(WmT, wc * 32 + l15,      kb, 256);
      bf16x8 b1 = ldsFrag(WmT, wc * 32 + 16 + l15, kb, 256);
      #pragma unroll
      for (int fr = 0; fr < 2; ++fr) {
        bf16x8 a = ldsFrag(sA, rg2 * 32 + fr * 16 + l15, kb, 256);
        acc[fr][0] = MFMA(a, b0, acc[fr][0]);
        acc[fr][1] = MFMA(a, b1, acc[fr][1]);
      }
    }
    __syncthreads();
    // ---- v = xev + T + bm -> sA (bf16) ----
    #pragma unroll
    for (int fr = 0; fr < 2; ++fr)
      #pragma unroll
      for (int fc = 0; fc < 2; ++fc) {
        int col = wc * 32 + fc * 16 + l15;
        #pragma unroll
        for (int i = 0; i < 4; ++i) {
          int r = rg2 * 32 + fr * 16 + lg * 4 + i;
          float v = xev[fr][fc][i] + acc[fr][fc][i] + bmv[fc];
          *(unsigned short*)(sA + ((r * 256 + col * 2) ^ ((r & 7) << 4))) = f2bf(v);
        }
      }
    __syncthreads();
    // ---- phase B: O = v @ We ----
    #pragma unroll
    for (int fr = 0; fr < 2; ++fr)
      #pragma unroll
      for (int fc = 0; fc < 2; ++fc) acc[fr][fc] = (f32x4){0.f, 0.f, 0.f, 0.f};
    #pragma unroll
    for (int ks = 0; ks < 4; ++ks) {
      int kb = ks * 64 + lg * 16;
      bf16x8 b0 = ldsFrag(WeT, wc * 32 + l15,      kb, 256);
      bf16x8 b1 = ldsFrag(WeT, wc * 32 + 16 + l15, kb, 256);
      #pragma unroll
      for (int fr = 0; fr < 2; ++fr) {
        bf16x8 a = ldsFrag(sA, rg2 * 32 + fr * 16 + l15, kb, 256);
        acc[fr][0] = MFMA(a, b0, acc[fr][0]);
        acc[fr][1] = MFMA(a, b1, acc[fr][1]);
      }
    }
    __syncthreads();   // sA free for next tile
    // ---- epilogue ----
    #pragma unroll
    for (int fr = 0; fr < 2; ++fr)
      #pragma unroll
      for (int fc = 0; fc < 2; ++fc) {
        int col = wc * 32 + fc * 16 + l15;
        #pragma unroll
        for (int i = 0; i < 4; ++i) {
          int r = rg2 * 32 + fr * 16 + lg * 4 + i;
          float o = acc[fr][fc][i] + bev[fc];
          if (doReluOut) o = fmaxf(o, 0.f);
          xeOut[(size_t)(rowBase + r) * ND + col] = o;
        }
      }
  }
}

// ====== fused readout: out = relu(relu(x@W1+b1)@W2+b2).W3 + b3  (512 thr, 3 barriers/tile) ======
__global__ __launch_bounds__(512, 2) void k_ro_fused(
    const float* __restrict__ inF, float* __restrict__ out, int nTiles,
    const char* __restrict__ W1Img, const float* __restrict__ b1,
    const char* __restrict__ W2Img, const float* __restrict__ b2,
    const float* __restrict__ W3, const float* __restrict__ b3)
{
  __shared__ __align__(16) char W1T[256 * 256];   // 64 KB
  __shared__ __align__(16) char W2T[128 * 512];   // 64 KB
  __shared__ __align__(16) char sA[32 * 256];     // 8 KB
  __shared__ __align__(16) char h1[32 * 512];     // 16 KB
  __shared__ float red[2][32][8];                 // 2 KB  -> 154 KB, 1 block/CU
  const int t = threadIdx.x;
  {
    const u32x4* s1 = (const u32x4*)W1Img;
    const u32x4* s2 = (const u32x4*)W2Img;
    u32x4* d1 = (u32x4*)W1T;
    u32x4* d2 = (u32x4*)W2T;
    for (int i = t; i < 4096; i += 512) { d1[i] = s1[i]; d2[i] = s2[i]; }
  }
  const int w   = t >> 6;           // wave 0..7
  const int l   = t & 63;
  const int l15 = l & 15;
  const int lg  = l >> 4;
  float b1v[2];
  #pragma unroll
  for (int fc = 0; fc < 2; ++fc) b1v[fc] = b1[w * 32 + fc * 16 + l15];
  const float b2v = b2[w * 16 + l15];
  const float w3v = W3[w * 16 + l15];
  const float b3v = b3[0];
  const int srow = t >> 4;          // 32 rows, 16 thr/row
  // prefetch first tile into registers
  float4 pv0, pv1;
  int tile = blockIdx.x;
  if (tile < nTiles) {
    const float4* p = (const float4*)(inF + (size_t)((tile << 5) + srow) * ND + (t & 15) * 8);
    pv0 = p[0]; pv1 = p[1];
  }
  __syncthreads();   // weights staged

  int par = 0;
  int prevRow = -1;
  for (; tile < nTiles; tile += gridDim.x) {
    const int rowBase = tile << 5;
    // ---- write sA from prefetched regs ----
    {
      unsigned short tmp[8];
      tmp[0] = f2bf(pv0.x); tmp[1] = f2bf(pv0.y); tmp[2] = f2bf(pv0.z); tmp[3] = f2bf(pv0.w);
      tmp[4] = f2bf(pv1.x); tmp[5] = f2bf(pv1.y); tmp[6] = f2bf(pv1.z); tmp[7] = f2bf(pv1.w);
      *(u32x4*)(sA + ((srow * 256 + (t & 15) * 16) ^ ((srow & 7) << 4))) = *(u32x4*)tmp;
    }
    __syncthreads();                                   // B1: sA ready
    // ---- deferred out-store for previous tile ----
    if (prevRow >= 0 && t < 32) {
      float s = b3v;
      #pragma unroll
      for (int q = 0; q < 8; ++q) s += red[par ^ 1][t][q];
      out[prevRow + t] = s;
    }
    // ---- prefetch next tile x into regs (latency hides under MFMA phases) ----
    {
      int nt2 = tile + (int)gridDim.x;
      if (nt2 < nTiles) {
        const float4* p = (const float4*)(inF + (size_t)((nt2 << 5) + srow) * ND + (t & 15) * 8);
        pv0 = p[0]; pv1 = p[1];
      }
    }
    // ---- phase 1: h1 = relu(x @ W1 + b1)   (32 x 256) ----
    {
      f32x4 acc[2][2];
      #pragma unroll
      for (int fr = 0; fr < 2; ++fr)
        #pragma unroll
        for (int fc = 0; fc < 2; ++fc) acc[fr][fc] = (f32x4){0.f, 0.f, 0.f, 0.f};
      #pragma unroll
      for (int ks = 0; ks < 4; ++ks) {
        int kb = ks * 64 + lg * 16;
        bf16x8 a0 = ldsFrag(sA, l15,      kb, 256);
        bf16x8 a1 = ldsFrag(sA, 16 + l15, kb, 256);
        bf16x8 b0 = ldsFrag(W1T, w * 32 + l15,      kb, 256);
        bf16x8 b1f = ldsFrag(W1T, w * 32 + 16 + l15, kb, 256);
        acc[0][0] = MFMA(a0, b0, acc[0][0]);
        acc[0][1] = MFMA(a0, b1f, acc[0][1]);
        acc[1][0] = MFMA(a1, b0, acc[1][0]);
        acc[1][1] = MFMA(a1, b1f, acc[1][1]);
      }
      __syncthreads();                                 // B2: sA reads + prev h1 reads done
      #pragma unroll
      for (int fr = 0; fr < 2; ++fr)
        #pragma unroll
        for (int fc = 0; fc < 2; ++fc) {
          int col = w * 32 + fc * 16 + l15;
          #pragma unroll
          for (int i = 0; i < 4; ++i) {
            int r = fr * 16 + lg * 4 + i;
            float o = fmaxf(acc[fr][fc][i] + b1v[fc], 0.f);
            *(unsigned short*)(h1 + ((r * 512 + col * 2) ^ ((r & 7) << 4))) = f2bf(o);
          }
        }
    }
    __syncthreads();                                   // B3: h1 ready
    // ---- phase 2: h2 = relu(h1 @ W2 + b2); p = h2 . W3 -> red[par] ----
    {
      f32x4 acc[2];
      acc[0] = (f32x4){0.f, 0.f, 0.f, 0.f};
      acc[1] = (f32x4){0.f, 0.f, 0.f, 0.f};
      #pragma unroll
      for (int ks = 0; ks < 8; ++ks) {
        int kb = ks * 64 + lg * 16;
        bf16x8 a0 = ldsFrag(h1, l15,      kb, 512);
        bf16x8 a1 = ldsFrag(h1, 16 + l15, kb, 512);
        bf16x8 bb = ldsFrag(W2T, w * 16 + l15, kb, 512);
        acc[0] = MFMA(a0, bb, acc[0]);
        acc[1] = MFMA(a1, bb, acc[1]);
      }
      #pragma unroll
      for (int fr = 0; fr < 2; ++fr)
        #pragma unroll
        for (int i = 0; i < 4; ++i) {
          float p = fmaxf(acc[fr][i] + b2v, 0.f) * w3v;
          p += __shfl_xor(p, 1);
          p += __shfl_xor(p, 2);
          p += __shfl_xor(p, 4);
          p += __shfl_xor(p, 8);
          if (l15 == 0) red[par][fr * 16 + lg * 4 + i][w] = p;
        }
    }
    prevRow = rowBase;
    par ^= 1;
    // no barrier here: next tile's sA write doesn't conflict with phase-2 (h1/W2T) reads;
    // red[par^1] read is gated by next B1.
  }
  __syncthreads();
  if (prevRow >= 0 && t < 32) {
    float s = b3v;
    #pragma unroll
    for (int q = 0; q < 8; ++q) s += red[par ^ 1][t][q];
    out[prevRow + t] = s;
  }
}

extern "C" void kernel_launch(void* const* d_in, const int* in_sizes, int n_in,
                              void* d_out, int out_size, void* d_ws, size_t ws_size,
                              hipStream_t stream)
{
  const float* x1     = (const float*)d_in[0];
  const float* x2     = (const float*)d_in[1];
  const float* Ac     = (const float*)d_in[2];
  const int*   edge   = (const int*)d_in[3];
  const float* node_W = (const float*)d_in[4];
  const float* node_b = (const float*)d_in[5];
  const float* mlp_W  = (const float*)d_in[6];
  const float* mlp_b  = (const float*)d_in[7];
  const float* egL_W  = (const float*)d_in[8];
  const float* egL_b  = (const float*)d_in[9];
  const float* nro_W1 = (const float*)d_in[10];
  const float* nro_b1 = (const float*)d_in[11];
  const float* nro_W2 = (const float*)d_in[12];
  const float* nro_b2 = (const float*)d_in[13];
  const float* nro_W3 = (const float*)d_in[14];
  const float* nro_b3 = (const float*)d_in[15];
  const float* ero_W1 = (const float*)d_in[16];
  const float* ero_b1 = (const float*)d_in[17];
  const float* ero_W2 = (const float*)d_in[18];
  const float* ero_b2 = (const float*)d_in[19];
  const float* ero_W3 = (const float*)d_in[20];
  const float* ero_b3 = (const float*)d_in[21];
  float* out = (float*)d_out;

  const size_t xnElems = (size_t)NB * NT * 2 * ND;       // 8,388,608
  const size_t xeElems = (size_t)NB * NM * 4 * ND;       // 134,217,728
  const size_t wBytes  = 3 * 128 * 128 * 2 * 2            // Wm, We images
                       + 2 * (128 * 256 * 2)              // nro W1, W2
                       + 2 * (128 * 256 * 2);             // ero W1, W2
  if (ws_size < (xnElems * 2 + xeElems) * sizeof(float) + wBytes) return;

  float* xnA = (float*)d_ws;
  float* xnB = xnA + xnElems;
  float* xe  = xnB + xnElems;
  char*  wWm = (char*)(xe + xeElems);
  char*  wWe = wWm + 3 * 128 * 128 * 2;
  char*  wN1 = wWe + 3 * 128 * 128 * 2;
  char*  wN2 = wN1 + 128 * 256 * 2;
  char*  wE1 = wN2 + 128 * 256 * 2;
  char*  wE2 = wE1 + 128 * 256 * 2;

  // CSR scratch lives in d_out (readouts overwrite it at the end)
  int* deg    = (int*)d_out;
  int* off    = deg + NT;
  int* cursor = off + NT + 1;
  int* csr    = cursor + NT;

  // weight prep (once)
  k_prep<<<24, 256, 0, stream>>>(mlp_W, wWm, 128, 128, 4, 11, 3 * 2048);
  k_prep<<<24, 256, 0, stream>>>(egL_W, wWe, 128, 128, 4, 11, 3 * 2048);
  k_prep<<<16, 256, 0, stream>>>(nro_W1, wN1, 128, 256, 4, 12, 4096);
  k_prep<<<16, 256, 0, stream>>>(nro_W2, wN2, 256, 128, 5, 12, 4096);
  k_prep<<<16, 256, 0, stream>>>(ero_W1, wE1, 128, 256, 4, 12, 4096);
  k_prep<<<16, 256, 0, stream>>>(ero_W2, wE2, 256, 128, 5, 12, 4096);

  hipMemsetAsync(deg, 0, NT * sizeof(int), stream);
  k_csr_count<<<NM / 256, 256, 0, stream>>>(edge, deg);
  k_csr_scan<<<1, 64, 0, stream>>>(deg, off, cursor);
  k_csr_fill<<<NM / 256, 256, 0, stream>>>(edge, cursor, csr);
  k_csr_sort<<<NT / 256, 256, 0, stream>>>(off, csr);

  const int eTiles = (NB * NM * 4) / 64;   // 16384
  // layer 0 (reads x1/x2 directly)
  k_node<<<2048, 256, 0, stream>>>(x1, xnA, Ac, edge, off, csr, node_W, node_b, 0);
  k_edge_mfma<<<512, 512, 0, stream>>>(xnA, x2, xe, edge,
                                       wWm, mlp_b, wWe, egL_b, 1, eTiles);
  // layer 1
  k_node<<<2048, 256, 0, stream>>>(xnA, xnB, Ac, edge, off, csr,
                                   node_W + ND * ND, node_b + ND, 1);
  k_edge_mfma<<<512, 512, 0, stream>>>(xnB, xe, xe, edge,
                                       wWm + 128 * 128 * 2, mlp_b + ND,
                                       wWe + 128 * 128 * 2, egL_b + ND, 1, eTiles);
  // layer 2
  k_node<<<2048, 256, 0, stream>>>(xnB, xnA, Ac, edge, off, csr,
                                   node_W + 2 * ND * ND, node_b + 2 * ND, 1);
  k_edge_mfma<<<512, 512, 0, stream>>>(xnA, xe, xe, edge,
                                       wWm + 2 * 128 * 128 * 2, mlp_b + 2 * ND,
                                       wWe + 2 * 128 * 128 * 2, egL_b + 2 * ND, 0, eTiles);
  // fused readouts
  k_ro_fused<<<512, 512, 0, stream>>>(xnA, out, (NB * NT * 2) / 32,
                                      wN1, nro_b1, wN2, nro_b2, nro_W3, nro_b3);
  k_ro_fused<<<512, 512, 0, stream>>>(xe, out + NB * NT * 2, (NB * NM * 4) / 32,
                                      wE1, ero_b1, wE2, ero_b2, ero_W3, ero_b3);
}

// Round 7
// 1391.235 us; speedup vs baseline: 7.4069x; 1.1094x over previous
//
#include <hip/hip_runtime.h>

#define NB 8
#define NT 4096
#define NM 32768
#define ND 128

typedef __attribute__((ext_vector_type(8))) short bf16x8;
typedef __attribute__((ext_vector_type(4))) float f32x4;
typedef __attribute__((ext_vector_type(4))) unsigned int u32x4;

#define MFMA(a,b,c) __builtin_amdgcn_mfma_f32_16x16x32_bf16(a,b,c,0,0,0)

// ---- bf16 helpers (RNE) ----
__device__ __forceinline__ unsigned short f2bf(float x) {
  unsigned u = __float_as_uint(x);
  u += 0x7FFFu + ((u >> 16) & 1u);
  return (unsigned short)(u >> 16);
}
__device__ __forceinline__ float bf2f(unsigned short h) {
  return __uint_as_float(((unsigned)h) << 16);
}

// XOR-swizzled LDS fragment read: 8 consecutive bf16 at (row, kByte)
__device__ __forceinline__ bf16x8 ldsFrag(const char* lds, int row, int kByte, int rowStride) {
  return *(const bf16x8*)(lds + ((row * rowStride + kByte) ^ ((row & 7) << 4)));
}

// ============ weight prep: W[K][N] f32 -> pre-swizzled bf16 image [N][K] (T-layout) ============
__global__ __launch_bounds__(256) void k_prep(
    const float* __restrict__ W, char* __restrict__ dst,
    int K, int N, int khShift, int perShift, int total)
{
  int i = blockIdx.x * 256 + threadIdx.x;
  if (i >= total) return;
  int m  = i >> perShift;
  int j  = i & ((1 << perShift) - 1);
  int n  = j >> khShift;
  int kh = j & ((1 << khShift) - 1);
  int k0 = kh << 3;
  const float* Wm = W + (size_t)m * K * N;
  char* dm = dst + (size_t)m * K * N * 2;
  unsigned short tmp[8];
  #pragma unroll
  for (int jj = 0; jj < 8; ++jj) tmp[jj] = f2bf(Wm[(k0 + jj) * N + n]);
  *(u32x4*)(dm + ((n * K * 2 + k0 * 2) ^ ((n & 7) << 4))) = *(u32x4*)tmp;
}

// ================= CSR build (edges constant across layers; deterministic) =================
__global__ __launch_bounds__(256) void k_csr_count(const int* __restrict__ edge, int* deg) {
  int m = blockIdx.x * 256 + threadIdx.x;
  if (m < NM) atomicAdd(&deg[edge[m]], 1);
}
__global__ __launch_bounds__(64) void k_csr_scan(const int* __restrict__ deg,
                                                 int* __restrict__ off, int* __restrict__ cursor) {
  __shared__ int partial[64];
  int t = threadIdx.x;
  int base = t * 64;
  int sum = 0;
  for (int i = 0; i < 64; ++i) sum += deg[base + i];
  partial[t] = sum;
  __syncthreads();
  if (t == 0) {
    int run = 0;
    for (int i = 0; i < 64; ++i) { int v = partial[i]; partial[i] = run; run += v; }
  }
  __syncthreads();
  int run = partial[t];
  for (int i = 0; i < 64; ++i) {
    off[base + i] = run; cursor[base + i] = run;
    run += deg[base + i];
  }
  if (t == 63) off[NT] = NM;
}
__global__ __launch_bounds__(256) void k_csr_fill(const int* __restrict__ edge,
                                                  int* cursor, int* __restrict__ csr) {
  int m = blockIdx.x * 256 + threadIdx.x;
  if (m < NM) { int pos = atomicAdd(&cursor[edge[m]], 1); csr[pos] = m; }
}
__global__ __launch_bounds__(256) void k_csr_sort(const int* __restrict__ off, int* __restrict__ csr) {
  int n = blockIdx.x * 256 + threadIdx.x;
  if (n < NT) {
    int s = off[n], e = off[n + 1];
    for (int i = s + 1; i < e; ++i) {
      int v = csr[i]; int j = i - 1;
      while (j >= s && csr[j] > v) { csr[j + 1] = csr[j]; --j; }
      csr[j + 1] = v;
    }
  }
}

// ====== fused node layer: xnOut = (relu?(xnIn) + gatherCSR(xnIn)) @ W + b  (f32 GEMM) ======
__global__ __launch_bounds__(256) void k_node(
    const float* __restrict__ xnIn, float* __restrict__ xnOut,
    const float* __restrict__ A, const int* __restrict__ edge,
    const int* __restrict__ off, const int* __restrict__ csr,
    const float* __restrict__ W, const float* __restrict__ bias, int doReluIn)
{
  __shared__ float Ws[ND * ND];     // 64 KB
  __shared__ float xs[32][ND];      // 16 KB  -> 80 KB, 2 blocks/CU
  const int t = threadIdx.x;
  for (int i = t; i < ND * ND; i += 256) Ws[i] = W[i];

  const int rowBase = blockIdx.x << 5;
  {
    const int r  = t >> 3;
    const int c0 = (t & 7) << 4;
    const int grow = rowBase + r;
    const int ch   = grow & 1;
    const int node = (grow >> 1) & (NT - 1);
    const int b    = grow >> 13;
    f32x4 acc[4];
    {
      const float4* xr = (const float4*)(xnIn + (size_t)grow * ND + c0);
      #pragma unroll
      for (int q = 0; q < 4; ++q) {
        float4 v = xr[q];
        if (doReluIn) {
          v.x = fmaxf(v.x, 0.f); v.y = fmaxf(v.y, 0.f);
          v.z = fmaxf(v.z, 0.f); v.w = fmaxf(v.w, 0.f);
        }
        acc[q] = (f32x4){v.x, v.y, v.z, v.w};
      }
    }
    const int s = off[node], e = off[node + 1];
    for (int p = s; p < e; ++p) {
      int m = csr[p];
      float a = A[b * NM + m];
      int e1 = edge[NM + m];
      const float4* src = (const float4*)(xnIn + (size_t)(((b * NT + e1) << 1) + ch) * ND + c0);
      #pragma unroll
      for (int q = 0; q < 4; ++q) {
        float4 v = src[q];
        if (doReluIn) {
          v.x = fmaxf(v.x, 0.f); v.y = fmaxf(v.y, 0.f);
          v.z = fmaxf(v.z, 0.f); v.w = fmaxf(v.w, 0.f);
        }
        acc[q][0] = fmaf(a, v.x, acc[q][0]);
        acc[q][1] = fmaf(a, v.y, acc[q][1]);
        acc[q][2] = fmaf(a, v.z, acc[q][2]);
        acc[q][3] = fmaf(a, v.w, acc[q][3]);
      }
    }
    #pragma unroll
    for (int q = 0; q < 4; ++q) *(f32x4*)&xs[r][c0 + q * 4] = acc[q];
  }
  const int c4 = (t & 31) << 2;
  const int rg = t >> 5;
  float4 bv = *(const float4*)(bias + c4);
  __syncthreads();
  float acc[4][4];
  #pragma unroll
  for (int r = 0; r < 4; ++r)
    #pragma unroll
    for (int c = 0; c < 4; ++c) acc[r][c] = 0.f;
  for (int k = 0; k < ND; k += 4) {
    float4 sv[4];
    #pragma unroll
    for (int r = 0; r < 4; ++r) sv[r] = *(const float4*)&xs[(rg << 2) + r][k];
    #pragma unroll
    for (int j = 0; j < 4; ++j) {
      float4 w = *(const float4*)&Ws[(k + j) * ND + c4];
      #pragma unroll
      for (int r = 0; r < 4; ++r) {
        float s = ((const float*)&sv[r])[j];
        acc[r][0] += s * w.x; acc[r][1] += s * w.y;
        acc[r][2] += s * w.z; acc[r][3] += s * w.w;
      }
    }
  }
  #pragma unroll
  for (int r = 0; r < 4; ++r) {
    float4 o;
    o.x = acc[r][0] + bv.x; o.y = acc[r][1] + bv.y;
    o.z = acc[r][2] + bv.z; o.w = acc[r][3] + bv.w;
    *(float4*)&xnOut[(size_t)(rowBase + (rg << 2) + r) * ND + c4] = o;
  }
}

// ------ edge layer (MFMA, 512 thr): xeOut = relu?((xeIn+(ei+ej)@Wm+bm)@We+be), xe in bf16 ----
template<int IN_F32>
__global__ __launch_bounds__(512, 4) void k_edge_mfma(
    const float* __restrict__ xn,
    const float* __restrict__ xeInF, const unsigned short* __restrict__ xeInH,
    unsigned short* xeOut,
    const int* __restrict__ edge,
    const char* __restrict__ WmImg, const float* __restrict__ bm,
    const char* __restrict__ WeImg, const float* __restrict__ be,
    int doReluOut, int nTiles)
{
  __shared__ __align__(16) char WmT[128 * 256];   // 32 KB
  __shared__ __align__(16) char WeT[128 * 256];   // 32 KB
  __shared__ __align__(16) char sA[64 * 256];     // 16 KB -> 80 KB, 2 blocks/CU
  const int t = threadIdx.x;
  {
    const u32x4* sm = (const u32x4*)WmImg;
    const u32x4* se = (const u32x4*)WeImg;
    u32x4* dm = (u32x4*)WmT;
    u32x4* de = (u32x4*)WeT;
    for (int i = t; i < 2048; i += 512) { dm[i] = sm[i]; de[i] = se[i]; }
  }
  const int w   = t >> 6;          // 0..7
  const int l   = t & 63;
  const int l15 = l & 15;
  const int lg  = l >> 4;
  const int rg2 = w >> 2;          // row half (32 rows)
  const int wc  = w & 3;           // col quarter (32 cols)
  float bmv[2], bev[2];
  #pragma unroll
  for (int fc = 0; fc < 2; ++fc) {
    int col = wc * 32 + fc * 16 + l15;
    bmv[fc] = bm[col];
    bev[fc] = be[col];
  }
  const int srow = t >> 3;         // 64 rows, 8 threads/row
  __syncthreads();

  for (int tile = blockIdx.x; tile < nTiles; tile += gridDim.x) {
    const int rowBase = tile << 6;
    // ---- stage sA = bf16(xn[e0,ni] + xn[e1,nj])  (64 rows x 128) ----
    {
      int grow = rowBase + srow;
      int cch = grow & 3;
      int m = (grow >> 2) & (NM - 1);
      int b = grow >> 17;
      int e0 = edge[m], e1 = edge[NM + m];
      const float4* p0 = (const float4*)(xn + (size_t)((b * NT + e0) * 2 + (cch >> 1)) * ND);
      const float4* p1 = (const float4*)(xn + (size_t)((b * NT + e1) * 2 + (cch & 1)) * ND);
      #pragma unroll
      for (int hh = 0; hh < 2; ++hh) {
        int h = (t & 7) + hh * 8;          // 16B slot 0..15
        float4 a0 = p0[h * 2], a1 = p0[h * 2 + 1];
        float4 c0 = p1[h * 2], c1 = p1[h * 2 + 1];
        unsigned short tmp[8];
        tmp[0] = f2bf(a0.x + c0.x); tmp[1] = f2bf(a0.y + c0.y);
        tmp[2] = f2bf(a0.z + c0.z); tmp[3] = f2bf(a0.w + c0.w);
        tmp[4] = f2bf(a1.x + c1.x); tmp[5] = f2bf(a1.y + c1.y);
        tmp[6] = f2bf(a1.z + c1.z); tmp[7] = f2bf(a1.w + c1.w);
        *(u32x4*)(sA + ((srow * 256 + h * 16) ^ ((srow & 7) << 4))) = *(u32x4*)tmp;
      }
    }
    // ---- prefetch xe tile into registers (consumed after phase A) ----
    float xev[2][2][4];
    #pragma unroll
    for (int fr = 0; fr < 2; ++fr)
      #pragma unroll
      for (int fc = 0; fc < 2; ++fc) {
        int col = wc * 32 + fc * 16 + l15;
        #pragma unroll
        for (int i = 0; i < 4; ++i) {
          int r = rg2 * 32 + fr * 16 + lg * 4 + i;
          size_t idx = (size_t)(rowBase + r) * ND + col;
          xev[fr][fc][i] = IN_F32 ? xeInF[idx] : bf2f(xeInH[idx]);
        }
      }
    __syncthreads();
    // ---- phase A: T = sA @ Wm ----
    f32x4 acc[2][2];
    #pragma unroll
    for (int fr = 0; fr < 2; ++fr)
      #pragma unroll
      for (int fc = 0; fc < 2; ++fc) acc[fr][fc] = (f32x4){0.f, 0.f, 0.f, 0.f};
    #pragma unroll
    for (int ks = 0; ks < 4; ++ks) {
      int kb = ks * 64 + lg * 16;
      bf16x8 b0 = ldsFrag(WmT, wc * 32 + l15,      kb, 256);
      bf16x8 b1 = ldsFrag(WmT, wc * 32 + 16 + l15, kb, 256);
      #pragma unroll
      for (int fr = 0; fr < 2; ++fr) {
        bf16x8 a = ldsFrag(sA, rg2 * 32 + fr * 16 + l15, kb, 256);
        acc[fr][0] = MFMA(a, b0, acc[fr][0]);
        acc[fr][1] = MFMA(a, b1, acc[fr][1]);
      }
    }
    __syncthreads();
    // ---- v = xev + T + bm -> sA (bf16) ----
    #pragma unroll
    for (int fr = 0; fr < 2; ++fr)
      #pragma unroll
      for (int fc = 0; fc < 2; ++fc) {
        int col = wc * 32 + fc * 16 + l15;
        #pragma unroll
        for (int i = 0; i < 4; ++i) {
          int r = rg2 * 32 + fr * 16 + lg * 4 + i;
          float v = xev[fr][fc][i] + acc[fr][fc][i] + bmv[fc];
          *(unsigned short*)(sA + ((r * 256 + col * 2) ^ ((r & 7) << 4))) = f2bf(v);
        }
      }
    __syncthreads();
    // ---- phase B: O = v @ We ----
    #pragma unroll
    for (int fr = 0; fr < 2; ++fr)
      #pragma unroll
      for (int fc = 0; fc < 2; ++fc) acc[fr][fc] = (f32x4){0.f, 0.f, 0.f, 0.f};
    #pragma unroll
    for (int ks = 0; ks < 4; ++ks) {
      int kb = ks * 64 + lg * 16;
      bf16x8 b0 = ldsFrag(WeT, wc * 32 + l15,      kb, 256);
      bf16x8 b1 = ldsFrag(WeT, wc * 32 + 16 + l15, kb, 256);
      #pragma unroll
      for (int fr = 0; fr < 2; ++fr) {
        bf16x8 a = ldsFrag(sA, rg2 * 32 + fr * 16 + l15, kb, 256);
        acc[fr][0] = MFMA(a, b0, acc[fr][0]);
        acc[fr][1] = MFMA(a, b1, acc[fr][1]);
      }
    }
    __syncthreads();   // sA free for next tile
    // ---- epilogue (bf16 store) ----
    #pragma unroll
    for (int fr = 0; fr < 2; ++fr)
      #pragma unroll
      for (int fc = 0; fc < 2; ++fc) {
        int col = wc * 32 + fc * 16 + l15;
        #pragma unroll
        for (int i = 0; i < 4; ++i) {
          int r = rg2 * 32 + fr * 16 + lg * 4 + i;
          float o = acc[fr][fc][i] + bev[fc];
          if (doReluOut) o = fmaxf(o, 0.f);
          xeOut[(size_t)(rowBase + r) * ND + col] = f2bf(o);
        }
      }
  }
}

// ====== fused readout: out = relu(relu(x@W1+b1)@W2+b2).W3 + b3  (512 thr, 3 barriers/tile) ======
template<int INBF16>
__global__ __launch_bounds__(512, 2) void k_ro_fused(
    const float* __restrict__ inF, const unsigned short* __restrict__ inH,
    float* __restrict__ out, int nTiles,
    const char* __restrict__ W1Img, const float* __restrict__ b1,
    const char* __restrict__ W2Img, const float* __restrict__ b2,
    const float* __restrict__ W3, const float* __restrict__ b3)
{
  __shared__ __align__(16) char W1T[256 * 256];   // 64 KB
  __shared__ __align__(16) char W2T[128 * 512];   // 64 KB
  __shared__ __align__(16) char sA[32 * 256];     // 8 KB
  __shared__ __align__(16) char h1[32 * 512];     // 16 KB
  __shared__ float red[2][32][8];                 // 2 KB  -> 154 KB, 1 block/CU
  const int t = threadIdx.x;
  {
    const u32x4* s1 = (const u32x4*)W1Img;
    const u32x4* s2 = (const u32x4*)W2Img;
    u32x4* d1 = (u32x4*)W1T;
    u32x4* d2 = (u32x4*)W2T;
    for (int i = t; i < 4096; i += 512) { d1[i] = s1[i]; d2[i] = s2[i]; }
  }
  const int w   = t >> 6;           // wave 0..7
  const int l   = t & 63;
  const int l15 = l & 15;
  const int lg  = l >> 4;
  float b1v[2];
  #pragma unroll
  for (int fc = 0; fc < 2; ++fc) b1v[fc] = b1[w * 32 + fc * 16 + l15];
  const float b2v = b2[w * 16 + l15];
  const float w3v = W3[w * 16 + l15];
  const float b3v = b3[0];
  const int srow = t >> 4;          // 32 rows, 16 thr/row
  // prefetch first tile into registers
  float4 pv0, pv1;
  u32x4 pvH;
  int tile = blockIdx.x;
  if (tile < nTiles) {
    if (INBF16) {
      pvH = *(const u32x4*)((const char*)inH + (size_t)((tile << 5) + srow) * 256 + (t & 15) * 16);
    } else {
      const float4* p = (const float4*)(inF + (size_t)((tile << 5) + srow) * ND + (t & 15) * 8);
      pv0 = p[0]; pv1 = p[1];
    }
  }
  __syncthreads();   // weights staged

  int par = 0;
  int prevRow = -1;
  for (; tile < nTiles; tile += gridDim.x) {
    const int rowBase = tile << 5;
    // ---- write sA from prefetched regs ----
    {
      u32x4 vv;
      if (INBF16) {
        vv = pvH;
      } else {
        unsigned short tmp[8];
        tmp[0] = f2bf(pv0.x); tmp[1] = f2bf(pv0.y); tmp[2] = f2bf(pv0.z); tmp[3] = f2bf(pv0.w);
        tmp[4] = f2bf(pv1.x); tmp[5] = f2bf(pv1.y); tmp[6] = f2bf(pv1.z); tmp[7] = f2bf(pv1.w);
        vv = *(u32x4*)tmp;
      }
      *(u32x4*)(sA + ((srow * 256 + (t & 15) * 16) ^ ((srow & 7) << 4))) = vv;
    }
    __syncthreads();                                   // B1: sA ready
    // ---- deferred out-store for previous tile ----
    if (prevRow >= 0 && t < 32) {
      float s = b3v;
      #pragma unroll
      for (int q = 0; q < 8; ++q) s += red[par ^ 1][t][q];
      out[prevRow + t] = s;
    }
    // ---- prefetch next tile into regs (latency hides under MFMA phases) ----
    {
      int nt2 = tile + (int)gridDim.x;
      if (nt2 < nTiles) {
        if (INBF16) {
          pvH = *(const u32x4*)((const char*)inH + (size_t)((nt2 << 5) + srow) * 256 + (t & 15) * 16);
        } else {
          const float4* p = (const float4*)(inF + (size_t)((nt2 << 5) + srow) * ND + (t & 15) * 8);
          pv0 = p[0]; pv1 = p[1];
        }
      }
    }
    // ---- phase 1: h1 = relu(x @ W1 + b1)   (32 x 256) ----
    {
      f32x4 acc[2][2];
      #pragma unroll
      for (int fr = 0; fr < 2; ++fr)
        #pragma unroll
        for (int fc = 0; fc < 2; ++fc) acc[fr][fc] = (f32x4){0.f, 0.f, 0.f, 0.f};
      #pragma unroll
      for (int ks = 0; ks < 4; ++ks) {
        int kb = ks * 64 + lg * 16;
        bf16x8 a0 = ldsFrag(sA, l15,      kb, 256);
        bf16x8 a1 = ldsFrag(sA, 16 + l15, kb, 256);
        bf16x8 b0 = ldsFrag(W1T, w * 32 + l15,      kb, 256);
        bf16x8 b1f = ldsFrag(W1T, w * 32 + 16 + l15, kb, 256);
        acc[0][0] = MFMA(a0, b0, acc[0][0]);
        acc[0][1] = MFMA(a0, b1f, acc[0][1]);
        acc[1][0] = MFMA(a1, b0, acc[1][0]);
        acc[1][1] = MFMA(a1, b1f, acc[1][1]);
      }
      __syncthreads();                                 // B2: sA reads + prev h1 reads done
      #pragma unroll
      for (int fr = 0; fr < 2; ++fr)
        #pragma unroll
        for (int fc = 0; fc < 2; ++fc) {
          int col = w * 32 + fc * 16 + l15;
          #pragma unroll
          for (int i = 0; i < 4; ++i) {
            int r = fr * 16 + lg * 4 + i;
            float o = fmaxf(acc[fr][fc][i] + b1v[fc], 0.f);
            *(unsigned short*)(h1 + ((r * 512 + col * 2) ^ ((r & 7) << 4))) = f2bf(o);
          }
        }
    }
    __syncthreads();                                   // B3: h1 ready
    // ---- phase 2: h2 = relu(h1 @ W2 + b2); p = h2 . W3 -> red[par] ----
    {
      f32x4 acc[2];
      acc[0] = (f32x4){0.f, 0.f, 0.f, 0.f};
      acc[1] = (f32x4){0.f, 0.f, 0.f, 0.f};
      #pragma unroll
      for (int ks = 0; ks < 8; ++ks) {
        int kb = ks * 64 + lg * 16;
        bf16x8 a0 = ldsFrag(h1, l15,      kb, 512);
        bf16x8 a1 = ldsFrag(h1, 16 + l15, kb, 512);
        bf16x8 bb = ldsFrag(W2T, w * 16 + l15, kb, 512);
        acc[0] = MFMA(a0, bb, acc[0]);
        acc[1] = MFMA(a1, bb, acc[1]);
      }
      #pragma unroll
      for (int fr = 0; fr < 2; ++fr)
        #pragma unroll
        for (int i = 0; i < 4; ++i) {
          float p = fmaxf(acc[fr][i] + b2v, 0.f) * w3v;
          p += __shfl_xor(p, 1);
          p += __shfl_xor(p, 2);
          p += __shfl_xor(p, 4);
          p += __shfl_xor(p, 8);
          if (l15 == 0) red[par][fr * 16 + lg * 4 + i][w] = p;
        }
    }
    prevRow = rowBase;
    par ^= 1;
  }
  __syncthreads();
  if (prevRow >= 0 && t < 32) {
    float s = b3v;
    #pragma unroll
    for (int q = 0; q < 8; ++q) s += red[par ^ 1][t][q];
    out[prevRow + t] = s;
  }
}

extern "C" void kernel_launch(void* const* d_in, const int* in_sizes, int n_in,
                              void* d_out, int out_size, void* d_ws, size_t ws_size,
                              hipStream_t stream)
{
  const float* x1     = (const float*)d_in[0];
  const float* x2     = (const float*)d_in[1];
  const float* Ac     = (const float*)d_in[2];
  const int*   edge   = (const int*)d_in[3];
  const float* node_W = (const float*)d_in[4];
  const float* node_b = (const float*)d_in[5];
  const float* mlp_W  = (const float*)d_in[6];
  const float* mlp_b  = (const float*)d_in[7];
  const float* egL_W  = (const float*)d_in[8];
  const float* egL_b  = (const float*)d_in[9];
  const float* nro_W1 = (const float*)d_in[10];
  const float* nro_b1 = (const float*)d_in[11];
  const float* nro_W2 = (const float*)d_in[12];
  const float* nro_b2 = (const float*)d_in[13];
  const float* nro_W3 = (const float*)d_in[14];
  const float* nro_b3 = (const float*)d_in[15];
  const float* ero_W1 = (const float*)d_in[16];
  const float* ero_b1 = (const float*)d_in[17];
  const float* ero_W2 = (const float*)d_in[18];
  const float* ero_b2 = (const float*)d_in[19];
  const float* ero_W3 = (const float*)d_in[20];
  const float* ero_b3 = (const float*)d_in[21];
  float* out = (float*)d_out;

  const size_t xnElems = (size_t)NB * NT * 2 * ND;       // 8,388,608
  const size_t xeElems = (size_t)NB * NM * 4 * ND;       // 134,217,728
  const size_t wBytes  = 3 * 128 * 128 * 2 * 2
                       + 4 * (128 * 256 * 2);
  if (ws_size < xnElems * 2 * sizeof(float) + xeElems * 2 + wBytes) return;

  float* xnA = (float*)d_ws;
  float* xnB = xnA + xnElems;
  unsigned short* xeH = (unsigned short*)(xnB + xnElems);   // bf16 xe
  char*  wWm = (char*)(xeH + xeElems);
  char*  wWe = wWm + 3 * 128 * 128 * 2;
  char*  wN1 = wWe + 3 * 128 * 128 * 2;
  char*  wN2 = wN1 + 128 * 256 * 2;
  char*  wE1 = wN2 + 128 * 256 * 2;
  char*  wE2 = wE1 + 128 * 256 * 2;

  // CSR scratch lives in d_out (readouts overwrite it at the end)
  int* deg    = (int*)d_out;
  int* off    = deg + NT;
  int* cursor = off + NT + 1;
  int* csr    = cursor + NT;

  // weight prep (once)
  k_prep<<<24, 256, 0, stream>>>(mlp_W, wWm, 128, 128, 4, 11, 3 * 2048);
  k_prep<<<24, 256, 0, stream>>>(egL_W, wWe, 128, 128, 4, 11, 3 * 2048);
  k_prep<<<16, 256, 0, stream>>>(nro_W1, wN1, 128, 256, 4, 12, 4096);
  k_prep<<<16, 256, 0, stream>>>(nro_W2, wN2, 256, 128, 5, 12, 4096);
  k_prep<<<16, 256, 0, stream>>>(ero_W1, wE1, 128, 256, 4, 12, 4096);
  k_prep<<<16, 256, 0, stream>>>(ero_W2, wE2, 256, 128, 5, 12, 4096);

  hipMemsetAsync(deg, 0, NT * sizeof(int), stream);
  k_csr_count<<<NM / 256, 256, 0, stream>>>(edge, deg);
  k_csr_scan<<<1, 64, 0, stream>>>(deg, off, cursor);
  k_csr_fill<<<NM / 256, 256, 0, stream>>>(edge, cursor, csr);
  k_csr_sort<<<NT / 256, 256, 0, stream>>>(off, csr);

  const int eTiles = (NB * NM * 4) / 64;   // 16384
  // layer 0 (reads x1/x2 directly)
  k_node<<<2048, 256, 0, stream>>>(x1, xnA, Ac, edge, off, csr, node_W, node_b, 0);
  k_edge_mfma<1><<<512, 512, 0, stream>>>(xnA, x2, nullptr, xeH, edge,
                                          wWm, mlp_b, wWe, egL_b, 1, eTiles);
  // layer 1
  k_node<<<2048, 256, 0, stream>>>(xnA, xnB, Ac, edge, off, csr,
                                   node_W + ND * ND, node_b + ND, 1);
  k_edge_mfma<0><<<512, 512, 0, stream>>>(xnB, nullptr, xeH, xeH, edge,
                                          wWm + 128 * 128 * 2, mlp_b + ND,
                                          wWe + 128 * 128 * 2, egL_b + ND, 1, eTiles);
  // layer 2
  k_node<<<2048, 256, 0, stream>>>(xnB, xnA, Ac, edge, off, csr,
                                   node_W + 2 * ND * ND, node_b + 2 * ND, 1);
  k_edge_mfma<0><<<512, 512, 0, stream>>>(xnA, nullptr, xeH, xeH, edge,
                                          wWm + 2 * 128 * 128 * 2, mlp_b + 2 * ND,
                                          wWe + 2 * 128 * 128 * 2, egL_b + 2 * ND, 0, eTiles);
  // fused readouts
  k_ro_fused<0><<<512, 512, 0, stream>>>(xnA, nullptr, out, (NB * NT * 2) / 32,
                                         wN1, nro_b1, wN2, nro_b2, nro_W3, nro_b3);
  k_ro_fused<1><<<512, 512, 0, stream>>>(nullptr, xeH, out + NB * NT * 2, (NB * NM * 4) / 32,
                                         wE1, ero_b1, wE2, ero_b2, ero_W3, ero_b3);
}

// Round 8
// 1289.995 us; speedup vs baseline: 7.9882x; 1.0785x over previous
//
#include <hip/hip_runtime.h>

#define NB 8
#define NT 4096
#define NM 32768
#define ND 128

typedef __attribute__((ext_vector_type(8))) short bf16x8;
typedef __attribute__((ext_vector_type(4))) float f32x4;
typedef __attribute__((ext_vector_type(4))) unsigned int u32x4;

#define MFMA(a,b,c) __builtin_amdgcn_mfma_f32_16x16x32_bf16(a,b,c,0,0,0)

// ---- bf16 helpers (RNE) ----
__device__ __forceinline__ unsigned short f2bf(float x) {
  unsigned u = __float_as_uint(x);
  u += 0x7FFFu + ((u >> 16) & 1u);
  return (unsigned short)(u >> 16);
}
__device__ __forceinline__ float bf2f(unsigned short h) {
  return __uint_as_float(((unsigned)h) << 16);
}

// XOR-swizzled LDS fragment read: 8 consecutive bf16 at (row, kByte)
__device__ __forceinline__ bf16x8 ldsFrag(const char* lds, int row, int kByte, int rowStride) {
  return *(const bf16x8*)(lds + ((row * rowStride + kByte) ^ ((row & 7) << 4)));
}

// ============ weight prep: W[K][N] f32 -> pre-swizzled bf16 image [N][K] (T-layout) ============
__global__ __launch_bounds__(256) void k_prep(
    const float* __restrict__ W, char* __restrict__ dst,
    int K, int N, int khShift, int perShift, int total)
{
  int i = blockIdx.x * 256 + threadIdx.x;
  if (i >= total) return;
  int m  = i >> perShift;
  int j  = i & ((1 << perShift) - 1);
  int n  = j >> khShift;
  int kh = j & ((1 << khShift) - 1);
  int k0 = kh << 3;
  const float* Wm = W + (size_t)m * K * N;
  char* dm = dst + (size_t)m * K * N * 2;
  unsigned short tmp[8];
  #pragma unroll
  for (int jj = 0; jj < 8; ++jj) tmp[jj] = f2bf(Wm[(k0 + jj) * N + n]);
  *(u32x4*)(dm + ((n * K * 2 + k0 * 2) ^ ((n & 7) << 4))) = *(u32x4*)tmp;
}

// ================= CSR build (edges constant across layers; deterministic) =================
__global__ __launch_bounds__(256) void k_csr_count(const int* __restrict__ edge, int* deg) {
  int m = blockIdx.x * 256 + threadIdx.x;
  if (m < NM) atomicAdd(&deg[edge[m]], 1);
}
__global__ __launch_bounds__(64) void k_csr_scan(const int* __restrict__ deg,
                                                 int* __restrict__ off, int* __restrict__ cursor) {
  __shared__ int partial[64];
  int t = threadIdx.x;
  int base = t * 64;
  int sum = 0;
  for (int i = 0; i < 64; ++i) sum += deg[base + i];
  partial[t] = sum;
  __syncthreads();
  if (t == 0) {
    int run = 0;
    for (int i = 0; i < 64; ++i) { int v = partial[i]; partial[i] = run; run += v; }
  }
  __syncthreads();
  int run = partial[t];
  for (int i = 0; i < 64; ++i) {
    off[base + i] = run; cursor[base + i] = run;
    run += deg[base + i];
  }
  if (t == 63) off[NT] = NM;
}
__global__ __launch_bounds__(256) void k_csr_fill(const int* __restrict__ edge,
                                                  int* cursor, int* __restrict__ csr) {
  int m = blockIdx.x * 256 + threadIdx.x;
  if (m < NM) { int pos = atomicAdd(&cursor[edge[m]], 1); csr[pos] = m; }
}
__global__ __launch_bounds__(256) void k_csr_sort(const int* __restrict__ off, int* __restrict__ csr) {
  int n = blockIdx.x * 256 + threadIdx.x;
  if (n < NT) {
    int s = off[n], e = off[n + 1];
    for (int i = s + 1; i < e; ++i) {
      int v = csr[i]; int j = i - 1;
      while (j >= s && csr[j] > v) { csr[j + 1] = csr[j]; --j; }
      csr[j + 1] = v;
    }
  }
}

// ====== fused node layer (MFMA): xnOut = (relu?(xnIn) + gatherCSR(xnIn)) @ W + b ======
__global__ __launch_bounds__(256, 4) void k_node(
    const float* __restrict__ xnIn, float* __restrict__ xnOut,
    const float* __restrict__ A, const int* __restrict__ edge,
    const int* __restrict__ off, const int* __restrict__ csr,
    const char* __restrict__ WImg, const float* __restrict__ bias,
    int doReluIn, int nTiles)
{
  __shared__ __align__(16) char WT[128 * 256];   // 32 KB bf16 swz
  __shared__ __align__(16) char xs[32 * 256];    // 8 KB bf16 swz -> 40 KB, 4 blocks/CU
  const int t = threadIdx.x;
  {
    const u32x4* s = (const u32x4*)WImg;
    u32x4* d = (u32x4*)WT;
    for (int i = t; i < 2048; i += 256) d[i] = s[i];
  }
  const int w   = t >> 6;     // wave 0..3 -> cols w*32..+31
  const int l   = t & 63;
  const int l15 = l & 15;
  const int lg  = l >> 4;
  float bv2[2];
  #pragma unroll
  for (int fc = 0; fc < 2; ++fc) bv2[fc] = bias[w * 32 + fc * 16 + l15];
  const int gr = t >> 3;          // gather row 0..31
  const int c0 = (t & 7) << 4;    // gather col block of 16
  __syncthreads();

  for (int tile = blockIdx.x; tile < nTiles; tile += gridDim.x) {
    const int rowBase = tile << 5;
    // ---- gather phase: 8 threads/row, 16 f32 acc each; emit bf16 into xs ----
    {
      const int grow = rowBase + gr;
      const int ch   = grow & 1;
      const int node = (grow >> 1) & (NT - 1);
      const int b    = grow >> 13;
      f32x4 acc[4];
      {
        const float4* xr = (const float4*)(xnIn + (size_t)grow * ND + c0);
        #pragma unroll
        for (int q = 0; q < 4; ++q) {
          float4 v = xr[q];
          if (doReluIn) {
            v.x = fmaxf(v.x, 0.f); v.y = fmaxf(v.y, 0.f);
            v.z = fmaxf(v.z, 0.f); v.w = fmaxf(v.w, 0.f);
          }
          acc[q] = (f32x4){v.x, v.y, v.z, v.w};
        }
      }
      const int s = off[node], e = off[node + 1];
      for (int p = s; p < e; ++p) {
        int m = csr[p];
        float a = A[b * NM + m];
        int e1 = edge[NM + m];
        const float4* src = (const float4*)(xnIn + (size_t)(((b * NT + e1) << 1) + ch) * ND + c0);
        #pragma unroll
        for (int q = 0; q < 4; ++q) {
          float4 v = src[q];
          if (doReluIn) {
            v.x = fmaxf(v.x, 0.f); v.y = fmaxf(v.y, 0.f);
            v.z = fmaxf(v.z, 0.f); v.w = fmaxf(v.w, 0.f);
          }
          acc[q][0] = fmaf(a, v.x, acc[q][0]);
          acc[q][1] = fmaf(a, v.y, acc[q][1]);
          acc[q][2] = fmaf(a, v.z, acc[q][2]);
          acc[q][3] = fmaf(a, v.w, acc[q][3]);
        }
      }
      unsigned short tmp[8];
      #pragma unroll
      for (int q = 0; q < 2; ++q)
        #pragma unroll
        for (int j = 0; j < 4; ++j) tmp[q * 4 + j] = f2bf(acc[q][j]);
      *(u32x4*)(xs + ((gr * 256 + c0 * 2) ^ ((gr & 7) << 4))) = *(u32x4*)tmp;
      #pragma unroll
      for (int q = 0; q < 2; ++q)
        #pragma unroll
        for (int j = 0; j < 4; ++j) tmp[q * 4 + j] = f2bf(acc[2 + q][j]);
      *(u32x4*)(xs + ((gr * 256 + c0 * 2 + 16) ^ ((gr & 7) << 4))) = *(u32x4*)tmp;
    }
    __syncthreads();
    // ---- MFMA GEMM: 32x128 = xs @ W ----
    f32x4 acc2[2][2];
    #pragma unroll
    for (int fr = 0; fr < 2; ++fr)
      #pragma unroll
      for (int fc = 0; fc < 2; ++fc) acc2[fr][fc] = (f32x4){0.f, 0.f, 0.f, 0.f};
    #pragma unroll
    for (int ks = 0; ks < 4; ++ks) {
      int kb = ks * 64 + lg * 16;
      bf16x8 b0 = ldsFrag(WT, w * 32 + l15,      kb, 256);
      bf16x8 b1 = ldsFrag(WT, w * 32 + 16 + l15, kb, 256);
      bf16x8 a0 = ldsFrag(xs, l15,      kb, 256);
      bf16x8 a1 = ldsFrag(xs, 16 + l15, kb, 256);
      acc2[0][0] = MFMA(a0, b0, acc2[0][0]);
      acc2[0][1] = MFMA(a0, b1, acc2[0][1]);
      acc2[1][0] = MFMA(a1, b0, acc2[1][0]);
      acc2[1][1] = MFMA(a1, b1, acc2[1][1]);
    }
    __syncthreads();   // xs free for next tile
    #pragma unroll
    for (int fr = 0; fr < 2; ++fr)
      #pragma unroll
      for (int fc = 0; fc < 2; ++fc) {
        int col = w * 32 + fc * 16 + l15;
        #pragma unroll
        for (int i = 0; i < 4; ++i) {
          int r = fr * 16 + lg * 4 + i;
          xnOut[(size_t)(rowBase + r) * ND + col] = acc2[fr][fc][i] + bv2[fc];
        }
      }
  }
}

// ------ edge layer (MFMA, 512 thr): xeOut = relu?((xeIn+(ei+ej)@Wm+bm)@We+be), xe in bf16 ----
template<int IN_F32>
__global__ __launch_bounds__(512, 4) void k_edge_mfma(
    const float* __restrict__ xn,
    const float* __restrict__ xeInF, const unsigned short* __restrict__ xeInH,
    unsigned short* xeOut,
    const int* __restrict__ edge,
    const char* __restrict__ WmImg, const float* __restrict__ bm,
    const char* __restrict__ WeImg, const float* __restrict__ be,
    int doReluOut, int nTiles)
{
  __shared__ __align__(16) char WmT[128 * 256];   // 32 KB
  __shared__ __align__(16) char WeT[128 * 256];   // 32 KB
  __shared__ __align__(16) char sA[64 * 256];     // 16 KB -> 80 KB, 2 blocks/CU
  const int t = threadIdx.x;
  {
    const u32x4* sm = (const u32x4*)WmImg;
    const u32x4* se = (const u32x4*)WeImg;
    u32x4* dm = (u32x4*)WmT;
    u32x4* de = (u32x4*)WeT;
    for (int i = t; i < 2048; i += 512) { dm[i] = sm[i]; de[i] = se[i]; }
  }
  const int w   = t >> 6;          // 0..7
  const int l   = t & 63;
  const int l15 = l & 15;
  const int lg  = l >> 4;
  const int rg2 = w >> 2;          // row half (32 rows)
  const int wc  = w & 3;           // col quarter (32 cols)
  float bmv[2], bev[2];
  #pragma unroll
  for (int fc = 0; fc < 2; ++fc) {
    int col = wc * 32 + fc * 16 + l15;
    bmv[fc] = bm[col];
    bev[fc] = be[col];
  }
  const int srow = t >> 3;         // 64 rows, 8 threads/row
  __syncthreads();

  for (int tile = blockIdx.x; tile < nTiles; tile += gridDim.x) {
    const int rowBase = tile << 6;
    // ---- stage sA = bf16(xn[e0,ni] + xn[e1,nj])  (64 rows x 128) ----
    {
      int grow = rowBase + srow;
      int cch = grow & 3;
      int m = (grow >> 2) & (NM - 1);
      int b = grow >> 17;
      int e0 = edge[m], e1 = edge[NM + m];
      const float4* p0 = (const float4*)(xn + (size_t)((b * NT + e0) * 2 + (cch >> 1)) * ND);
      const float4* p1 = (const float4*)(xn + (size_t)((b * NT + e1) * 2 + (cch & 1)) * ND);
      #pragma unroll
      for (int hh = 0; hh < 2; ++hh) {
        int h = (t & 7) + hh * 8;          // 16B slot 0..15
        float4 a0 = p0[h * 2], a1 = p0[h * 2 + 1];
        float4 c0 = p1[h * 2], c1 = p1[h * 2 + 1];
        unsigned short tmp[8];
        tmp[0] = f2bf(a0.x + c0.x); tmp[1] = f2bf(a0.y + c0.y);
        tmp[2] = f2bf(a0.z + c0.z); tmp[3] = f2bf(a0.w + c0.w);
        tmp[4] = f2bf(a1.x + c1.x); tmp[5] = f2bf(a1.y + c1.y);
        tmp[6] = f2bf(a1.z + c1.z); tmp[7] = f2bf(a1.w + c1.w);
        *(u32x4*)(sA + ((srow * 256 + h * 16) ^ ((srow & 7) << 4))) = *(u32x4*)tmp;
      }
    }
    // ---- prefetch xe tile into registers (consumed after phase A) ----
    float xev[2][2][4];
    #pragma unroll
    for (int fr = 0; fr < 2; ++fr)
      #pragma unroll
      for (int fc = 0; fc < 2; ++fc) {
        int col = wc * 32 + fc * 16 + l15;
        #pragma unroll
        for (int i = 0; i < 4; ++i) {
          int r = rg2 * 32 + fr * 16 + lg * 4 + i;
          size_t idx = (size_t)(rowBase + r) * ND + col;
          xev[fr][fc][i] = IN_F32 ? xeInF[idx] : bf2f(xeInH[idx]);
        }
      }
    __syncthreads();
    // ---- phase A: T = sA @ Wm ----
    f32x4 acc[2][2];
    #pragma unroll
    for (int fr = 0; fr < 2; ++fr)
      #pragma unroll
      for (int fc = 0; fc < 2; ++fc) acc[fr][fc] = (f32x4){0.f, 0.f, 0.f, 0.f};
    #pragma unroll
    for (int ks = 0; ks < 4; ++ks) {
      int kb = ks * 64 + lg * 16;
      bf16x8 b0 = ldsFrag(WmT, wc * 32 + l15,      kb, 256);
      bf16x8 b1 = ldsFrag(WmT, wc * 32 + 16 + l15, kb, 256);
      #pragma unroll
      for (int fr = 0; fr < 2; ++fr) {
        bf16x8 a = ldsFrag(sA, rg2 * 32 + fr * 16 + l15, kb, 256);
        acc[fr][0] = MFMA(a, b0, acc[fr][0]);
        acc[fr][1] = MFMA(a, b1, acc[fr][1]);
      }
    }
    __syncthreads();
    // ---- v = xev + T + bm -> sA (bf16) ----
    #pragma unroll
    for (int fr = 0; fr < 2; ++fr)
      #pragma unroll
      for (int fc = 0; fc < 2; ++fc) {
        int col = wc * 32 + fc * 16 + l15;
        #pragma unroll
        for (int i = 0; i < 4; ++i) {
          int r = rg2 * 32 + fr * 16 + lg * 4 + i;
          float v = xev[fr][fc][i] + acc[fr][fc][i] + bmv[fc];
          *(unsigned short*)(sA + ((r * 256 + col * 2) ^ ((r & 7) << 4))) = f2bf(v);
        }
      }
    __syncthreads();
    // ---- phase B: O = v @ We ----
    #pragma unroll
    for (int fr = 0; fr < 2; ++fr)
      #pragma unroll
      for (int fc = 0; fc < 2; ++fc) acc[fr][fc] = (f32x4){0.f, 0.f, 0.f, 0.f};
    #pragma unroll
    for (int ks = 0; ks < 4; ++ks) {
      int kb = ks * 64 + lg * 16;
      bf16x8 b0 = ldsFrag(WeT, wc * 32 + l15,      kb, 256);
      bf16x8 b1 = ldsFrag(WeT, wc * 32 + 16 + l15, kb, 256);
      #pragma unroll
      for (int fr = 0; fr < 2; ++fr) {
        bf16x8 a = ldsFrag(sA, rg2 * 32 + fr * 16 + l15, kb, 256);
        acc[fr][0] = MFMA(a, b0, acc[fr][0]);
        acc[fr][1] = MFMA(a, b1, acc[fr][1]);
      }
    }
    __syncthreads();   // sA free for next tile
    // ---- epilogue (bf16 store) ----
    #pragma unroll
    for (int fr = 0; fr < 2; ++fr)
      #pragma unroll
      for (int fc = 0; fc < 2; ++fc) {
        int col = wc * 32 + fc * 16 + l15;
        #pragma unroll
        for (int i = 0; i < 4; ++i) {
          int r = rg2 * 32 + fr * 16 + lg * 4 + i;
          float o = acc[fr][fc][i] + bev[fc];
          if (doReluOut) o = fmaxf(o, 0.f);
          xeOut[(size_t)(rowBase + r) * ND + col] = f2bf(o);
        }
      }
  }
}

// ====== fused readout, weights in REGISTERS: out = relu(relu(x@W1+b1)@W2+b2).W3 + b3 ======
template<int INBF16>
__global__ __launch_bounds__(512, 4) void k_ro_fused(
    const float* __restrict__ inF, const unsigned short* __restrict__ inH,
    float* __restrict__ out, int nTiles,
    const char* __restrict__ W1Img, const float* __restrict__ b1,
    const char* __restrict__ W2Img, const float* __restrict__ b2,
    const float* __restrict__ W3, const float* __restrict__ b3)
{
  __shared__ __align__(16) char sA[32 * 256];     // 8 KB
  __shared__ __align__(16) char h1[32 * 512];     // 16 KB
  __shared__ float red[2][32][8];                 // 2 KB  -> 26 KB, 2+ blocks/CU
  const int t = threadIdx.x;
  const int w   = t >> 6;           // wave 0..7
  const int l   = t & 63;
  const int l15 = l & 15;
  const int lg  = l >> 4;
  // ---- loop-invariant weight fragments -> registers ----
  bf16x8 w1f[4][2];   // [ks][fc]  W1 cols w*32..+31
  #pragma unroll
  for (int ks = 0; ks < 4; ++ks)
    #pragma unroll
    for (int fc = 0; fc < 2; ++fc) {
      int n = w * 32 + fc * 16 + l15;
      int kb = ks * 64 + lg * 16;
      w1f[ks][fc] = *(const bf16x8*)(W1Img + ((n * 256 + kb) ^ ((n & 7) << 4)));
    }
  bf16x8 w2f[8];      // W2 cols w*16..+15
  #pragma unroll
  for (int ks = 0; ks < 8; ++ks) {
    int n = w * 16 + l15;
    int kb = ks * 64 + lg * 16;
    w2f[ks] = *(const bf16x8*)(W2Img + ((n * 512 + kb) ^ ((n & 7) << 4)));
  }
  float b1v[2];
  #pragma unroll
  for (int fc = 0; fc < 2; ++fc) b1v[fc] = b1[w * 32 + fc * 16 + l15];
  const float b2v = b2[w * 16 + l15];
  const float w3v = W3[w * 16 + l15];
  const float b3v = b3[0];
  const int srow = t >> 4;          // 32 rows, 16 thr/row
  // prefetch first tile
  float4 pv0, pv1;
  u32x4 pvH;
  int tile = blockIdx.x;
  if (tile < nTiles) {
    if (INBF16) {
      pvH = *(const u32x4*)((const char*)inH + (size_t)((tile << 5) + srow) * 256 + (t & 15) * 16);
    } else {
      const float4* p = (const float4*)(inF + (size_t)((tile << 5) + srow) * ND + (t & 15) * 8);
      pv0 = p[0]; pv1 = p[1];
    }
  }

  int par = 0;
  int prevRow = -1;
  for (; tile < nTiles; tile += gridDim.x) {
    const int rowBase = tile << 5;
    // ---- write sA from prefetched regs ----
    {
      u32x4 vv;
      if (INBF16) {
        vv = pvH;
      } else {
        unsigned short tmp[8];
        tmp[0] = f2bf(pv0.x); tmp[1] = f2bf(pv0.y); tmp[2] = f2bf(pv0.z); tmp[3] = f2bf(pv0.w);
        tmp[4] = f2bf(pv1.x); tmp[5] = f2bf(pv1.y); tmp[6] = f2bf(pv1.z); tmp[7] = f2bf(pv1.w);
        vv = *(u32x4*)tmp;
      }
      *(u32x4*)(sA + ((srow * 256 + (t & 15) * 16) ^ ((srow & 7) << 4))) = vv;
    }
    __syncthreads();                                   // B1: sA ready
    // ---- deferred out-store for previous tile ----
    if (prevRow >= 0 && t < 32) {
      float s = b3v;
      #pragma unroll
      for (int q = 0; q < 8; ++q) s += red[par ^ 1][t][q];
      out[prevRow + t] = s;
    }
    // ---- prefetch next tile ----
    {
      int nt2 = tile + (int)gridDim.x;
      if (nt2 < nTiles) {
        if (INBF16) {
          pvH = *(const u32x4*)((const char*)inH + (size_t)((nt2 << 5) + srow) * 256 + (t & 15) * 16);
        } else {
          const float4* p = (const float4*)(inF + (size_t)((nt2 << 5) + srow) * ND + (t & 15) * 8);
          pv0 = p[0]; pv1 = p[1];
        }
      }
    }
    // ---- phase 1: h1 = relu(x @ W1 + b1)   (32 x 256), B from regs ----
    {
      f32x4 acc[2][2];
      #pragma unroll
      for (int fr = 0; fr < 2; ++fr)
        #pragma unroll
        for (int fc = 0; fc < 2; ++fc) acc[fr][fc] = (f32x4){0.f, 0.f, 0.f, 0.f};
      #pragma unroll
      for (int ks = 0; ks < 4; ++ks) {
        int kb = ks * 64 + lg * 16;
        bf16x8 a0 = ldsFrag(sA, l15,      kb, 256);
        bf16x8 a1 = ldsFrag(sA, 16 + l15, kb, 256);
        acc[0][0] = MFMA(a0, w1f[ks][0], acc[0][0]);
        acc[0][1] = MFMA(a0, w1f[ks][1], acc[0][1]);
        acc[1][0] = MFMA(a1, w1f[ks][0], acc[1][0]);
        acc[1][1] = MFMA(a1, w1f[ks][1], acc[1][1]);
      }
      __syncthreads();                                 // B2: sA + prev h1 reads done
      #pragma unroll
      for (int fr = 0; fr < 2; ++fr)
        #pragma unroll
        for (int fc = 0; fc < 2; ++fc) {
          int col = w * 32 + fc * 16 + l15;
          #pragma unroll
          for (int i = 0; i < 4; ++i) {
            int r = fr * 16 + lg * 4 + i;
            float o = fmaxf(acc[fr][fc][i] + b1v[fc], 0.f);
            *(unsigned short*)(h1 + ((r * 512 + col * 2) ^ ((r & 7) << 4))) = f2bf(o);
          }
        }
    }
    __syncthreads();                                   // B3: h1 ready
    // ---- phase 2: h2 = relu(h1 @ W2 + b2); p = h2 . W3 -> red[par], B from regs ----
    {
      f32x4 acc[2];
      acc[0] = (f32x4){0.f, 0.f, 0.f, 0.f};
      acc[1] = (f32x4){0.f, 0.f, 0.f, 0.f};
      #pragma unroll
      for (int ks = 0; ks < 8; ++ks) {
        int kb = ks * 64 + lg * 16;
        bf16x8 a0 = ldsFrag(h1, l15,      kb, 512);
        bf16x8 a1 = ldsFrag(h1, 16 + l15, kb, 512);
        acc[0] = MFMA(a0, w2f[ks], acc[0]);
        acc[1] = MFMA(a1, w2f[ks], acc[1]);
      }
      #pragma unroll
      for (int fr = 0; fr < 2; ++fr)
        #pragma unroll
        for (int i = 0; i < 4; ++i) {
          float p = fmaxf(acc[fr][i] + b2v, 0.f) * w3v;
          p += __shfl_xor(p, 1);
          p += __shfl_xor(p, 2);
          p += __shfl_xor(p, 4);
          p += __shfl_xor(p, 8);
          if (l15 == 0) red[par][fr * 16 + lg * 4 + i][w] = p;
        }
    }
    prevRow = rowBase;
    par ^= 1;
  }
  __syncthreads();
  if (prevRow >= 0 && t < 32) {
    float s = b3v;
    #pragma unroll
    for (int q = 0; q < 8; ++q) s += red[par ^ 1][t][q];
    out[prevRow + t] = s;
  }
}

extern "C" void kernel_launch(void* const* d_in, const int* in_sizes, int n_in,
                              void* d_out, int out_size, void* d_ws, size_t ws_size,
                              hipStream_t stream)
{
  const float* x1     = (const float*)d_in[0];
  const float* x2     = (const float*)d_in[1];
  const float* Ac     = (const float*)d_in[2];
  const int*   edge   = (const int*)d_in[3];
  const float* node_W = (const float*)d_in[4];
  const float* node_b = (const float*)d_in[5];
  const float* mlp_W  = (const float*)d_in[6];
  const float* mlp_b  = (const float*)d_in[7];
  const float* egL_W  = (const float*)d_in[8];
  const float* egL_b  = (const float*)d_in[9];
  const float* nro_W1 = (const float*)d_in[10];
  const float* nro_b1 = (const float*)d_in[11];
  const float* nro_W2 = (const float*)d_in[12];
  const float* nro_b2 = (const float*)d_in[13];
  const float* nro_W3 = (const float*)d_in[14];
  const float* nro_b3 = (const float*)d_in[15];
  const float* ero_W1 = (const float*)d_in[16];
  const float* ero_b1 = (const float*)d_in[17];
  const float* ero_W2 = (const float*)d_in[18];
  const float* ero_b2 = (const float*)d_in[19];
  const float* ero_W3 = (const float*)d_in[20];
  const float* ero_b3 = (const float*)d_in[21];
  float* out = (float*)d_out;

  const size_t xnElems = (size_t)NB * NT * 2 * ND;       // 8,388,608
  const size_t xeElems = (size_t)NB * NM * 4 * ND;       // 134,217,728
  const size_t wBytes  = 3 * 128 * 128 * 2 * 3            // Wm, We, node W images
                       + 4 * (128 * 256 * 2);
  if (ws_size < xnElems * 2 * sizeof(float) + xeElems * 2 + wBytes) return;

  float* xnA = (float*)d_ws;
  float* xnB = xnA + xnElems;
  unsigned short* xeH = (unsigned short*)(xnB + xnElems);   // bf16 xe
  char*  wWm = (char*)(xeH + xeElems);
  char*  wWe = wWm + 3 * 128 * 128 * 2;
  char*  wNd = wWe + 3 * 128 * 128 * 2;
  char*  wN1 = wNd + 3 * 128 * 128 * 2;
  char*  wN2 = wN1 + 128 * 256 * 2;
  char*  wE1 = wN2 + 128 * 256 * 2;
  char*  wE2 = wE1 + 128 * 256 * 2;

  // CSR scratch lives in d_out (readouts overwrite it at the end)
  int* deg    = (int*)d_out;
  int* off    = deg + NT;
  int* cursor = off + NT + 1;
  int* csr    = cursor + NT;

  // weight prep (once)
  k_prep<<<24, 256, 0, stream>>>(mlp_W, wWm, 128, 128, 4, 11, 3 * 2048);
  k_prep<<<24, 256, 0, stream>>>(egL_W, wWe, 128, 128, 4, 11, 3 * 2048);
  k_prep<<<24, 256, 0, stream>>>(node_W, wNd, 128, 128, 4, 11, 3 * 2048);
  k_prep<<<16, 256, 0, stream>>>(nro_W1, wN1, 128, 256, 4, 12, 4096);
  k_prep<<<16, 256, 0, stream>>>(nro_W2, wN2, 256, 128, 5, 12, 4096);
  k_prep<<<16, 256, 0, stream>>>(ero_W1, wE1, 128, 256, 4, 12, 4096);
  k_prep<<<16, 256, 0, stream>>>(ero_W2, wE2, 256, 128, 5, 12, 4096);

  hipMemsetAsync(deg, 0, NT * sizeof(int), stream);
  k_csr_count<<<NM / 256, 256, 0, stream>>>(edge, deg);
  k_csr_scan<<<1, 64, 0, stream>>>(deg, off, cursor);
  k_csr_fill<<<NM / 256, 256, 0, stream>>>(edge, cursor, csr);
  k_csr_sort<<<NT / 256, 256, 0, stream>>>(off, csr);

  const int eTiles = (NB * NM * 4) / 64;   // 16384
  const int nTilesN = (NB * NT * 2) / 32;  // 2048
  // layer 0 (reads x1/x2 directly)
  k_node<<<1024, 256, 0, stream>>>(x1, xnA, Ac, edge, off, csr, wNd, node_b, 0, nTilesN);
  k_edge_mfma<1><<<512, 512, 0, stream>>>(xnA, x2, nullptr, xeH, edge,
                                          wWm, mlp_b, wWe, egL_b, 1, eTiles);
  // layer 1
  k_node<<<1024, 256, 0, stream>>>(xnA, xnB, Ac, edge, off, csr,
                                   wNd + 128 * 128 * 2, node_b + ND, 1, nTilesN);
  k_edge_mfma<0><<<512, 512, 0, stream>>>(xnB, nullptr, xeH, xeH, edge,
                                          wWm + 128 * 128 * 2, mlp_b + ND,
                                          wWe + 128 * 128 * 2, egL_b + ND, 1, eTiles);
  // layer 2
  k_node<<<1024, 256, 0, stream>>>(xnB, xnA, Ac, edge, off, csr,
                                   wNd + 2 * 128 * 128 * 2, node_b + 2 * ND, 1, nTilesN);
  k_edge_mfma<0><<<512, 512, 0, stream>>>(xnA, nullptr, xeH, xeH, edge,
                                          wWm + 2 * 128 * 128 * 2, mlp_b + 2 * ND,
                                          wWe + 2 * 128 * 128 * 2, egL_b + 2 * ND, 0, eTiles);
  // fused readouts (weights in registers)
  k_ro_fused<0><<<1024, 512, 0, stream>>>(xnA, nullptr, out, (NB * NT * 2) / 32,
                                          wN1, nro_b1, wN2, nro_b2, nro_W3, nro_b3);
  k_ro_fused<1><<<1024, 512, 0, stream>>>(nullptr, xeH, out + NB * NT * 2, (NB * NM * 4) / 32,
                                          wE1, ero_b1, wE2, ero_b2, ero_W3, ero_b3);
}